// Round 3
// baseline (254.293 us; speedup 1.0000x reference)
//
#include <hip/hip_runtime.h>

// Problem constants: B=8, H=96, W=128, C=128, NS=4, with_shift=1
#define H 96
#define W 128
#define C 128
#define WSH 24
#define WSW 32
#define NTOK 768
#define SH 12
#define SW 16
#define KT 32        // keys per tile
#define NKT 24       // tiles per window (each tile = one spatial row)
#define PSTR 40      // P LDS row stride (ushorts)
// ws tile: K-frags 8KB (kc-major chunks) + V-frags 8KB (cb-major chunks, permuted keys)
#define TILE_USH 8192                  // 16384 B
#define WS_NEED (128L * NKT * TILE_USH * 2)  // 50,331,648 bytes

typedef __attribute__((ext_vector_type(8))) short short8;
typedef __attribute__((ext_vector_type(4))) float floatx4;

__device__ inline unsigned short f2bf(float f) {
  union { float f; unsigned u; } un; un.f = f;
  unsigned r = un.u + 0x7FFF + ((un.u >> 16) & 1);
  return (unsigned short)(r >> 16);
}

// window token -> global spatial offset (y*W + x), folding the shift-roll
__device__ inline int tok_off(int tok, int wh, int ww) {
  int r = tok >> 5;
  int cc = tok & 31;
  int y = wh * WSH + r + SH; if (y >= H) y -= H;
  int x = ww * WSW + cc + SW; if (x >= W) x -= W;
  return y * W + x;
}

// async global->LDS, 16B per lane, LDS dst = wave-uniform base + lane*16
__device__ inline void gll16(const void* g, void* lds) {
  __builtin_amdgcn_global_load_lds(
      (const __attribute__((address_space(1))) unsigned int*)g,
      (__attribute__((address_space(3))) unsigned int*)lds, 16, 0, 0);
}

// ---------------- prep: fp32 K,V -> bf16 MFMA-fragment tiles in ws ----------
// K section (4096 ush): chunk(kc,key,quad) at kc*1024 + (key*4+quad)*8 holds
//   K[key][kc*32+quad*8 .. +7]  -> lane (col,quad) b128 load is coalesced 1KB.
// V section (4096 ush): chunk(cb,col,quad) at 4096 + cb*512 + (col*4+quad)*8
//   holds V^T[ch=cb*16+col][pos quad*8..+7], pos p -> key (p&1)*16 + (p>>1)
//   (permuted to match packed P writes in main kernel).
// Block mapping is XCD-matched to attn_main: window w is written by blocks on
// XCD w>>4 (bid&7), the same XCD that reads it -> staged reads hit local L2.
__global__ __launch_bounds__(256) void prep_kernel(const float* __restrict__ k,
                                                   const float* __restrict__ v,
                                                   unsigned short* __restrict__ ws) {
  __shared__ unsigned short Vlds[KT][136];
  const int bid = blockIdx.x;               // 3072 blocks
  const int xcd = bid & 7;
  const int jj = bid >> 3;                  // 0..383
  const int w = xcd * 16 + (jj & 15);       // window 0..127, on XCD w>>4
  const int kt = jj >> 4;                   // 0..23
  const int batch = w >> 4, win = w & 15;
  const int wh = win >> 2, ww = win & 3;
  int y = wh * WSH + kt + SH; if (y >= H) y -= H;

  const int t = threadIdx.x;
  const int key = t >> 3;           // 0..31
  const int j = t & 7;              // channel group of 16
  const int c0 = j * 16;
  int x = ww * WSW + key + SW; if (x >= W) x -= W;
  const long src = ((long)batch * H * W + (long)y * W + x) * C + c0;
  unsigned short* tile = ws + ((long)w * NKT + kt) * TILE_USH;

  // K: convert 16 channels -> two fragment chunks (kc=j>>1, quads 2*(j&1), +1)
  {
    const float* kp = k + src;
    short8 s0, s1;
#pragma unroll
    for (int i = 0; i < 2; ++i) {
      floatx4 a = *(const floatx4*)(kp + i * 8);
      floatx4 b = *(const floatx4*)(kp + i * 8 + 4);
      s0[i*4+0] = (short)f2bf(a[0]); s0[i*4+1] = (short)f2bf(a[1]);
      s0[i*4+2] = (short)f2bf(a[2]); s0[i*4+3] = (short)f2bf(a[3]);
      s1[i*4+0] = (short)f2bf(b[0]); s1[i*4+1] = (short)f2bf(b[1]);
      s1[i*4+2] = (short)f2bf(b[2]); s1[i*4+3] = (short)f2bf(b[3]);
    }
    // re-interleave: chunk0 = ch c0..c0+7, chunk1 = ch c0+8..c0+15
    short8 o0, o1;
    o0[0]=s0[0]; o0[1]=s0[1]; o0[2]=s0[2]; o0[3]=s0[3]; o0[4]=s1[0]; o0[5]=s1[1]; o0[6]=s1[2]; o0[7]=s1[3];
    o1[0]=s0[4]; o1[1]=s0[5]; o1[2]=s0[6]; o1[3]=s0[7]; o1[4]=s1[4]; o1[5]=s1[5]; o1[6]=s1[6]; o1[7]=s1[7];
    const int kc = j >> 1;
    const int q2 = (j & 1) * 2;
    unsigned short* kout = tile + kc * 1024 + key * 32 + q2 * 8;
    *(short8*)(kout) = o0;        // quad q2
    *(short8*)(kout + 8) = o1;    // quad q2+1
  }
  // V: convert into LDS [key][ch]
  {
    const float* vp = v + src;
#pragma unroll
    for (int i = 0; i < 4; ++i) {
      floatx4 a = *(const floatx4*)(vp + i * 4);
      Vlds[key][c0 + i*4 + 0] = f2bf(a[0]);
      Vlds[key][c0 + i*4 + 1] = f2bf(a[1]);
      Vlds[key][c0 + i*4 + 2] = f2bf(a[2]);
      Vlds[key][c0 + i*4 + 3] = f2bf(a[3]);
    }
  }
  __syncthreads();
  // V fragment chunks, permuted key order
  {
    const int cb = t >> 5;
    const int rem = t & 31;
    const int col = rem >> 1, qh = rem & 1;
    const int ch = cb * 16 + col;
#pragma unroll
    for (int qs = 0; qs < 2; ++qs) {
      const int quad = qh * 2 + qs;
      short8 o;
#pragma unroll
      for (int i = 0; i < 8; ++i)
        o[i] = (short)Vlds[(i & 1) * 16 + quad * 4 + (i >> 1)][ch];
      *(short8*)(tile + 4096 + cb * 512 + (col * 4 + quad) * 8) = o;
    }
  }
}

// ---------------- main fused attention ---------------------------------------
// 512 blocks x 256 threads (4 waves). Wave = 48 q-rows (3 sets of 16); block
// covers 192 rows; 4 blocks per window. K/V tile (16KB) staged ONCE per block
// into double-buffered LDS via global_load_lds (ws layout is already linear
// lane order), T3 2-phase schedule: stage(next) at top, vmcnt(0)+barrier at
// bottom -> a full tile of compute hides the load latency. This replaces the
// per-wave global K/V streams (8x redundant, cross-XCD L3 latency) that made
// rounds 0-2 TLP-insensitive (1->2 waves/SIMD: +0%). P stays wave-private LDS.
__global__ __launch_bounds__(256, 2) void attn_main(const float* __restrict__ q,
                                                    const unsigned short* __restrict__ ws,
                                                    float* __restrict__ out) {
  __shared__ unsigned short Kv[2][TILE_USH];       // 32 KB double-buffered tile
  __shared__ unsigned short Ps[4][3][16 * PSTR];   // 15360 B

  // bid -> xcd-stable swizzle: window's 4 q-blocks share bid%8 (same XCD);
  // window w lands on XCD w>>4, matching prep's writer XCD.
  const int bid = blockIdx.x;
  const int x8 = bid & 7;
  const int i = bid >> 3;            // 0..63
  const int w = x8 * 16 + (i & 15);  // window 0..127
  const int qb = i >> 4;             // 0..3 (192 q each)
  const int batch = w >> 4, win = w & 15;
  const int wh = win >> 2, ww = win & 3;

  const int tid = threadIdx.x;
  const int wv = tid >> 6, lane = tid & 63;
  const int col = lane & 15, quad = lane >> 4;
  const long bbase = (long)batch * (H * W * C);
  const int qbase = qb * 192 + wv * 48;
  const int loff = (col * 4 + quad) * 8;   // fragment chunk offset (ushorts)

  const char* wtile = (const char*)(ws + (long)w * (NKT * TILE_USH));

  // stage tile kt into LDS buffer buf: 16 chunks of 1KB, 4 per wave
  auto stage = [&](int buf, int kt) {
    const char* g = wtile + ((long)kt << 14);
#pragma unroll
    for (int c = 0; c < 4; ++c) {
      const int chunk = wv * 4 + c;
      gll16(g + chunk * 1024 + lane * 16, &Kv[buf][chunk * 512]);
    }
  };

  stage(0, 0);   // overlap with Q prologue below

  // ---- Q fragments: 3 sets x 4 kc, kept in registers ----
  short8 qfrag[3][4];
#pragma unroll
  for (int s = 0; s < 3; ++s) {
    const int qtok = qbase + s * 16 + col;
    const float* qp = q + bbase + (long)tok_off(qtok, wh, ww) * C + quad * 8;
#pragma unroll
    for (int kc = 0; kc < 4; ++kc) {
      floatx4 a = *(const floatx4*)(qp + kc * 32);
      floatx4 b = *(const floatx4*)(qp + kc * 32 + 4);
      short8 v8;
      v8[0]=(short)f2bf(a[0]); v8[1]=(short)f2bf(a[1]); v8[2]=(short)f2bf(a[2]); v8[3]=(short)f2bf(a[3]);
      v8[4]=(short)f2bf(b[0]); v8[5]=(short)f2bf(b[1]); v8[6]=(short)f2bf(b[2]); v8[7]=(short)f2bf(b[3]);
      qfrag[s][kc] = v8;
    }
  }

  // ---- analytic mask regions (wave-uniform per set) ----
  int qreg[3];
#pragma unroll
  for (int s = 0; s < 3; ++s) {
    int t0 = qbase + s * 16;
    int rr_s = t0 >> 5;
    int qh = (wh == 3) ? ((rr_s >= SH) ? 2 : 1) : 0;
    int qw = (ww == 3) ? ((t0 & 16) ? 2 : 1) : 0;
    qreg[s] = qh * 3 + qw;
  }
  const int cw0 = (ww == 3) ? 1 : 0, cw1 = (ww == 3) ? 2 : 0;
  const float MNEG = -144.2695041f;  // -100*log2(e)
  const float SC2 = 0.12751739f;     // log2(e)/sqrt(128)

  floatx4 oacc[3][8];
#pragma unroll
  for (int s = 0; s < 3; ++s)
#pragma unroll
    for (int cb = 0; cb < 8; ++cb) oacc[s][cb] = (floatx4){0.f, 0.f, 0.f, 0.f};
  float lsum[3][4];
#pragma unroll
  for (int s = 0; s < 3; ++s)
#pragma unroll
    for (int r = 0; r < 4; ++r) lsum[s][r] = 0.f;

  // tile 0 staged & visible
  asm volatile("s_waitcnt vmcnt(0)" ::: "memory");
  __builtin_amdgcn_s_barrier();

  for (int kt = 0; kt < NKT; ++kt) {
    const int cur = kt & 1;
    // issue next tile's stage now; drained at bottom (full tile of cover)
    if (kt + 1 < NKT) stage(cur ^ 1, kt + 1);

    // K fragments from LDS (conflict-free: 64 lanes cover 1KB bijectively)
    short8 kf0[4], kf1[4];
#pragma unroll
    for (int kc = 0; kc < 4; ++kc) {
      kf0[kc] = *(const short8*)&Kv[cur][kc * 1024 + loff];
      kf1[kc] = *(const short8*)&Kv[cur][kc * 1024 + 512 + loff];
    }

    const int khb = (wh == 3) ? ((kt >= SH) ? 6 : 3) : 0;
    const int kr0 = khb + cw0, kr1 = khb + cw1;

    // ---- QK^T + softmax + packed P write, per set ----
#pragma unroll
    for (int s = 0; s < 3; ++s) {
      floatx4 a0 = (floatx4){0.f, 0.f, 0.f, 0.f};
      floatx4 a1 = (floatx4){0.f, 0.f, 0.f, 0.f};
#pragma unroll
      for (int kc = 0; kc < 4; ++kc) {
        a0 = __builtin_amdgcn_mfma_f32_16x16x32_bf16(qfrag[s][kc], kf0[kc], a0, 0, 0, 0);
        a1 = __builtin_amdgcn_mfma_f32_16x16x32_bf16(qfrag[s][kc], kf1[kc], a1, 0, 0, 0);
      }
      const float m0 = (qreg[s] == kr0) ? 0.f : MNEG;
      const float m1 = (qreg[s] == kr1) ? 0.f : MNEG;
#pragma unroll
      for (int r = 0; r < 4; ++r) {
        float p0 = __builtin_amdgcn_exp2f(fmaf(a0[r], SC2, m0));
        float p1 = __builtin_amdgcn_exp2f(fmaf(a1[r], SC2, m1));
        lsum[s][r] += p0 + p1;
        unsigned pk = (unsigned)f2bf(p0) | ((unsigned)f2bf(p1) << 16);
        *(unsigned*)&Ps[wv][s][(quad * 4 + r) * PSTR + 2 * col] = pk;
      }
    }

    // V fragments from LDS
    short8 vf[8];
#pragma unroll
    for (int cb = 0; cb < 8; ++cb)
      vf[cb] = *(const short8*)&Kv[cur][4096 + cb * 512 + loff];

    // ---- O += P V (wave-private P, lgkmcnt only) ----
#pragma unroll
    for (int s = 0; s < 3; ++s) {
      short8 pf = *(const short8*)&Ps[wv][s][col * PSTR + quad * 8];
#pragma unroll
      for (int cb = 0; cb < 8; ++cb)
        oacc[s][cb] = __builtin_amdgcn_mfma_f32_16x16x32_bf16(pf, vf[cb], oacc[s][cb], 0, 0, 0);
    }

    // next tile staged; previous readers done (within-wave lgkm drained above)
    if (kt + 1 < NKT) {
      asm volatile("s_waitcnt vmcnt(0)" ::: "memory");
      __builtin_amdgcn_s_barrier();
    }
  }

  // ---- epilogue: reduce l over the 16 cols, divide, store ----
#pragma unroll
  for (int s = 0; s < 3; ++s)
#pragma unroll
    for (int r = 0; r < 4; ++r) {
      float l = lsum[s][r];
      l += __shfl_xor(l, 1); l += __shfl_xor(l, 2);
      l += __shfl_xor(l, 4); l += __shfl_xor(l, 8);
      float inv = 1.0f / l;
      int tok = qbase + s * 16 + quad * 4 + r;
      float* op = out + bbase + (long)tok_off(tok, wh, ww) * C + col;
#pragma unroll
      for (int cb = 0; cb < 8; ++cb) op[cb * 16] = oacc[s][cb][r] * inv;
    }
}

// ---------------- fallback (self-contained, used only if ws too small) -------
#define KSTRF 136
#define VSTRF 40
#define PSTRF 40
__global__ __launch_bounds__(256, 2) void attn_fallback(
    const float* __restrict__ q, const float* __restrict__ k,
    const float* __restrict__ v, const float* __restrict__ mask,
    float* __restrict__ out) {
  __shared__ unsigned short Ks[KT * KSTRF];
  __shared__ unsigned short Vtl[C * VSTRF];
  __shared__ unsigned short Psf[4][16 * PSTRF];
  const int qtile = blockIdx.x;
  const int beta  = blockIdx.y;
  const int batch = beta >> 4;
  const int win   = beta & 15;
  const int wh = win >> 2, ww = win & 3;
  const int tid = threadIdx.x;
  const int wave = tid >> 6, lane = tid & 63;
  const int col = lane & 15, quad = lane >> 4;
  const long bbase = (long)batch * (H * W * C);
  const int qtok = qtile * 64 + wave * 16 + col;
  const float* qp = q + bbase + (long)tok_off(qtok, wh, ww) * C + quad * 8;
  short8 qfrag[4];
#pragma unroll
  for (int kc = 0; kc < 4; ++kc) {
    floatx4 a = *(const floatx4*)(qp + kc * 32);
    floatx4 b = *(const floatx4*)(qp + kc * 32 + 4);
    short8 s;
    s[0]=f2bf(a[0]); s[1]=f2bf(a[1]); s[2]=f2bf(a[2]); s[3]=f2bf(a[3]);
    s[4]=f2bf(b[0]); s[5]=f2bf(b[1]); s[6]=f2bf(b[2]); s[7]=f2bf(b[3]);
    qfrag[kc] = s;
  }
  floatx4 oacc[8];
#pragma unroll
  for (int i = 0; i < 8; ++i) oacc[i] = (floatx4){0.f,0.f,0.f,0.f};
  float mrow[4], lrow[4];
#pragma unroll
  for (int r = 0; r < 4; ++r) { mrow[r] = -1e30f; lrow[r] = 0.f; }
  const int skey = tid >> 3;
  const int sch  = (tid & 7) * 4;
  const float invscale = 0.088388347648318447f;
  const float* maskw = mask + (long)win * (NTOK * NTOK);
  const int qrow_m = qtile * 64 + wave * 16 + quad * 4;
  for (int kt = 0; kt < NKT; ++kt) {
    const int ktok0 = kt * KT;
    const long srow = bbase + (long)tok_off(ktok0 + skey, wh, ww) * C;
    const float* kp = k + srow;
    const float* vp = v + srow;
    __syncthreads();
#pragma unroll
    for (int j = 0; j < 4; ++j) {
      floatx4 f = *(const floatx4*)(kp + sch + j * 32);
      unsigned lo = (unsigned)f2bf(f[0]) | ((unsigned)f2bf(f[1]) << 16);
      unsigned hi = (unsigned)f2bf(f[2]) | ((unsigned)f2bf(f[3]) << 16);
      *(uint2*)&Ks[skey * KSTRF + sch + j * 32] = make_uint2(lo, hi);
    }
#pragma unroll
    for (int j = 0; j < 4; ++j) {
      floatx4 f = *(const floatx4*)(vp + sch + j * 32);
      int chb = sch + j * 32;
      Vtl[(chb + 0) * VSTRF + skey] = f2bf(f[0]);
      Vtl[(chb + 1) * VSTRF + skey] = f2bf(f[1]);
      Vtl[(chb + 2) * VSTRF + skey] = f2bf(f[2]);
      Vtl[(chb + 3) * VSTRF + skey] = f2bf(f[3]);
    }
    __syncthreads();
    floatx4 s0 = (floatx4){0.f,0.f,0.f,0.f};
    floatx4 s1 = (floatx4){0.f,0.f,0.f,0.f};
#pragma unroll
    for (int kc = 0; kc < 4; ++kc) {
      short8 k0 = *(const short8*)&Ks[col * KSTRF + kc * 32 + quad * 8];
      short8 k1 = *(const short8*)&Ks[(col + 16) * KSTRF + kc * 32 + quad * 8];
      s0 = __builtin_amdgcn_mfma_f32_16x16x32_bf16(qfrag[kc], k0, s0, 0, 0, 0);
      s1 = __builtin_amdgcn_mfma_f32_16x16x32_bf16(qfrag[kc], k1, s1, 0, 0, 0);
    }
    float mk0[4], mk1[4];
    const float* mp = maskw + (long)qrow_m * NTOK + ktok0 + col;
#pragma unroll
    for (int r = 0; r < 4; ++r) { mk0[r] = mp[r * NTOK]; mk1[r] = mp[r * NTOK + 16]; }
#pragma unroll
    for (int r = 0; r < 4; ++r) {
      float a0 = s0[r] * invscale + mk0[r];
      float a1 = s1[r] * invscale + mk1[r];
      float mx = fmaxf(a0, a1);
      mx = fmaxf(mx, __shfl_xor(mx, 1)); mx = fmaxf(mx, __shfl_xor(mx, 2));
      mx = fmaxf(mx, __shfl_xor(mx, 4)); mx = fmaxf(mx, __shfl_xor(mx, 8));
      float mnew = fmaxf(mrow[r], mx);
      float alpha = __expf(mrow[r] - mnew);
      float p0 = __expf(a0 - mnew);
      float p1 = __expf(a1 - mnew);
      float rs = p0 + p1;
      rs += __shfl_xor(rs, 1); rs += __shfl_xor(rs, 2);
      rs += __shfl_xor(rs, 4); rs += __shfl_xor(rs, 8);
      lrow[r] = lrow[r] * alpha + rs;
      mrow[r] = mnew;
#pragma unroll
      for (int cb = 0; cb < 8; ++cb) oacc[cb][r] *= alpha;
      Psf[wave][(quad * 4 + r) * PSTRF + col]      = f2bf(p0);
      Psf[wave][(quad * 4 + r) * PSTRF + 16 + col] = f2bf(p1);
    }
    __syncthreads();
    short8 pf = *(const short8*)&Psf[wave][col * PSTRF + quad * 8];
#pragma unroll
    for (int cb = 0; cb < 8; ++cb) {
      short8 vf = *(const short8*)&Vtl[(cb * 16 + col) * VSTRF + quad * 8];
      oacc[cb] = __builtin_amdgcn_mfma_f32_16x16x32_bf16(pf, vf, oacc[cb], 0, 0, 0);
    }
  }
#pragma unroll
  for (int r = 0; r < 4; ++r) {
    float inv_l = 1.0f / lrow[r];
    int tok = qtile * 64 + wave * 16 + quad * 4 + r;
    float* op = out + bbase + (long)tok_off(tok, wh, ww) * C + col;
#pragma unroll
    for (int cb = 0; cb < 8; ++cb) op[cb * 16] = oacc[cb][r] * inv_l;
  }
}

extern "C" void kernel_launch(void* const* d_in, const int* in_sizes, int n_in,
                              void* d_out, int out_size, void* d_ws, size_t ws_size,
                              hipStream_t stream) {
  const float* q    = (const float*)d_in[0];
  const float* k    = (const float*)d_in[1];
  const float* v    = (const float*)d_in[2];
  const float* mask = (const float*)d_in[3];
  float* out = (float*)d_out;
  if (ws_size >= (size_t)WS_NEED) {
    prep_kernel<<<128 * NKT, 256, 0, stream>>>(k, v, (unsigned short*)d_ws);
    attn_main<<<512, 256, 0, stream>>>(q, (const unsigned short*)d_ws, out);
  } else {
    attn_fallback<<<dim3(12, 128), dim3(256), 0, stream>>>(q, k, v, mask, out);
  }
}

// Round 4
// 251.541 us; speedup vs baseline: 1.0109x; 1.0109x over previous
//
#include <hip/hip_runtime.h>

// Problem constants: B=8, H=96, W=128, C=128, NS=4, with_shift=1
#define H 96
#define W 128
#define C 128
#define WSH 24
#define WSW 32
#define NTOK 768
#define SH 12
#define SW 16
#define KT 32        // keys per tile
#define NKT 24       // tiles per window (each tile = one spatial row)
#define PSTR 40      // P LDS row stride (ushorts)
// ws tile: K-frags 8KB + V-frags 8KB. Chunk order v2: within each 1KB region
// (16 keys x 4 quads), chunk index = quad*16+key == lane -> ds_read_b128 at
// byte lane*16 is linear & bank-conflict-free (old key*4+quad order aliased
// banks ~8-way: SQ_LDS_BANK_CONFLICT 3.7M in round 3).
#define TILE_USH 8192                  // 16384 B
#define WS_NEED (128L * NKT * TILE_USH * 2)  // 50,331,648 bytes

typedef __attribute__((ext_vector_type(8))) short short8;
typedef __attribute__((ext_vector_type(4))) float floatx4;

__device__ inline unsigned short f2bf(float f) {
  union { float f; unsigned u; } un; un.f = f;
  unsigned r = un.u + 0x7FFF + ((un.u >> 16) & 1);
  return (unsigned short)(r >> 16);
}

// window token -> global spatial offset (y*W + x), folding the shift-roll
__device__ inline int tok_off(int tok, int wh, int ww) {
  int r = tok >> 5;
  int cc = tok & 31;
  int y = wh * WSH + r + SH; if (y >= H) y -= H;
  int x = ww * WSW + cc + SW; if (x >= W) x -= W;
  return y * W + x;
}

// async global->LDS, 16B per lane, LDS dst = wave-uniform base + lane*16
__device__ inline void gll16(const void* g, void* lds) {
  __builtin_amdgcn_global_load_lds(
      (const __attribute__((address_space(1))) unsigned int*)g,
      (__attribute__((address_space(3))) unsigned int*)lds, 16, 0, 0);
}

// ---------------- prep: fp32 K,V -> bf16 MFMA-fragment tiles in ws ----------
// K section (4096 ush): per kc (1024 ush), two 512-ush halves (keys 0-15 /
//   16-31). Chunk (quad*16+keyh) at half*512 + (quad*16+keyh)*8 holds
//   K[key][kc*32+quad*8 .. +7]  -> lane l reads chunk l: linear, conflict-free.
// V section (4096 ush): chunk at 4096 + cb*512 + (quad*16+col)*8 holds
//   V^T[ch=cb*16+col][pos quad*8..+7], pos p -> key (p&1)*16 + (p>>1)
//   (permuted to match packed P writes in main kernel).
// Block mapping is XCD-matched to attn_main: window w is written by blocks on
// XCD w>>4 (bid&7), the same XCD that reads it -> staged reads hit local L2.
__global__ __launch_bounds__(256) void prep_kernel(const float* __restrict__ k,
                                                   const float* __restrict__ v,
                                                   unsigned short* __restrict__ ws) {
  __shared__ unsigned short Vlds[KT][136];
  const int bid = blockIdx.x;               // 3072 blocks
  const int xcd = bid & 7;
  const int jj = bid >> 3;                  // 0..383
  const int w = xcd * 16 + (jj & 15);       // window 0..127, on XCD w>>4
  const int kt = jj >> 4;                   // 0..23
  const int batch = w >> 4, win = w & 15;
  const int wh = win >> 2, ww = win & 3;
  int y = wh * WSH + kt + SH; if (y >= H) y -= H;

  const int t = threadIdx.x;
  const int key = t >> 3;           // 0..31
  const int j = t & 7;              // channel group of 16
  const int c0 = j * 16;
  int x = ww * WSW + key + SW; if (x >= W) x -= W;
  const long src = ((long)batch * H * W + (long)y * W + x) * C + c0;
  unsigned short* tile = ws + ((long)w * NKT + kt) * TILE_USH;

  // K: convert 16 channels -> two fragment chunks (kc=j>>1, quads 2*(j&1), +1)
  {
    const float* kp = k + src;
    short8 s0, s1;
#pragma unroll
    for (int i = 0; i < 2; ++i) {
      floatx4 a = *(const floatx4*)(kp + i * 8);
      floatx4 b = *(const floatx4*)(kp + i * 8 + 4);
      s0[i*4+0] = (short)f2bf(a[0]); s0[i*4+1] = (short)f2bf(a[1]);
      s0[i*4+2] = (short)f2bf(a[2]); s0[i*4+3] = (short)f2bf(a[3]);
      s1[i*4+0] = (short)f2bf(b[0]); s1[i*4+1] = (short)f2bf(b[1]);
      s1[i*4+2] = (short)f2bf(b[2]); s1[i*4+3] = (short)f2bf(b[3]);
    }
    // re-interleave: chunk0 = ch c0..c0+7, chunk1 = ch c0+8..c0+15
    short8 o0, o1;
    o0[0]=s0[0]; o0[1]=s0[1]; o0[2]=s0[2]; o0[3]=s0[3]; o0[4]=s1[0]; o0[5]=s1[1]; o0[6]=s1[2]; o0[7]=s1[3];
    o1[0]=s0[4]; o1[1]=s0[5]; o1[2]=s0[6]; o1[3]=s0[7]; o1[4]=s1[4]; o1[5]=s1[5]; o1[6]=s1[6]; o1[7]=s1[7];
    const int kc = j >> 1;
    const int q2 = (j & 1) * 2;
    const int half = key >> 4, keyh = key & 15;
    unsigned short* kout = tile + kc * 1024 + half * 512 + keyh * 8;
    *(short8*)(kout + (q2    ) * 128) = o0;   // chunk (q2*16+keyh)
    *(short8*)(kout + (q2 + 1) * 128) = o1;   // chunk ((q2+1)*16+keyh)
  }
  // V: convert into LDS [key][ch]
  {
    const float* vp = v + src;
#pragma unroll
    for (int i = 0; i < 4; ++i) {
      floatx4 a = *(const floatx4*)(vp + i * 4);
      Vlds[key][c0 + i*4 + 0] = f2bf(a[0]);
      Vlds[key][c0 + i*4 + 1] = f2bf(a[1]);
      Vlds[key][c0 + i*4 + 2] = f2bf(a[2]);
      Vlds[key][c0 + i*4 + 3] = f2bf(a[3]);
    }
  }
  __syncthreads();
  // V fragment chunks, permuted key order
  {
    const int cb = t >> 5;
    const int rem = t & 31;
    const int col = rem >> 1, qh = rem & 1;
    const int ch = cb * 16 + col;
#pragma unroll
    for (int qs = 0; qs < 2; ++qs) {
      const int quad = qh * 2 + qs;
      short8 o;
#pragma unroll
      for (int i = 0; i < 8; ++i)
        o[i] = (short)Vlds[(i & 1) * 16 + quad * 4 + (i >> 1)][ch];
      *(short8*)(tile + 4096 + cb * 512 + (quad * 16 + col) * 8) = o;
    }
  }
}

// ---------------- main fused attention ---------------------------------------
// 512 blocks x 256 threads (4 waves). Wave = 48 q-rows (3 sets of 16); block
// covers 192 rows; 4 blocks per window. K/V tile (16KB) staged ONCE per block
// into TRIPLE-buffered LDS via global_load_lds; stage(kt+2) issued at top of
// iter kt, bottom waits counted vmcnt(4) (kt+1 landed; kt+2's 4 loads are the
// only newer FIFO entries) + raw s_barrier -> 2 full tiles of compute cover
// each stage, no vmcnt(0) drain in steady state. ds_reads are linear
// (chunk==lane) -> bank-conflict-free. P stays wave-private LDS.
__global__ __launch_bounds__(256, 2) void attn_main(const float* __restrict__ q,
                                                    const unsigned short* __restrict__ ws,
                                                    float* __restrict__ out) {
  __shared__ unsigned short Kv[3][TILE_USH];       // 48 KB triple-buffered
  __shared__ unsigned short Ps[4][3][16 * PSTR];   // 15360 B

  // bid -> xcd-stable swizzle: window's 4 q-blocks share bid%8 (same XCD);
  // window w lands on XCD w>>4, matching prep's writer XCD.
  const int bid = blockIdx.x;
  const int x8 = bid & 7;
  const int i = bid >> 3;            // 0..63
  const int w = x8 * 16 + (i & 15);  // window 0..127
  const int qb = i >> 4;             // 0..3 (192 q each)
  const int batch = w >> 4, win = w & 15;
  const int wh = win >> 2, ww = win & 3;

  const int tid = threadIdx.x;
  const int wv = tid >> 6, lane = tid & 63;
  const int col = lane & 15, quad = lane >> 4;
  const long bbase = (long)batch * (H * W * C);
  const int qbase = qb * 192 + wv * 48;
  const int loff = lane * 8;         // fragment chunk offset (ushorts), linear

  const char* wtile = (const char*)(ws + (long)w * (NKT * TILE_USH));

  // stage tile kt into LDS buffer buf: 16 chunks of 1KB, 4 per wave
  auto stage = [&](int buf, int kt) {
    const char* g = wtile + ((long)kt << 14);
#pragma unroll
    for (int c = 0; c < 4; ++c) {
      const int chunk = wv * 4 + c;
      gll16(g + chunk * 1024 + lane * 16, &Kv[buf][chunk * 512]);
    }
  };

  stage(0, 0);
  stage(1, 1);   // both overlap with Q prologue below

  // ---- Q fragments: 3 sets x 4 kc, kept in registers ----
  short8 qfrag[3][4];
#pragma unroll
  for (int s = 0; s < 3; ++s) {
    const int qtok = qbase + s * 16 + col;
    const float* qp = q + bbase + (long)tok_off(qtok, wh, ww) * C + quad * 8;
#pragma unroll
    for (int kc = 0; kc < 4; ++kc) {
      floatx4 a = *(const floatx4*)(qp + kc * 32);
      floatx4 b = *(const floatx4*)(qp + kc * 32 + 4);
      short8 v8;
      v8[0]=(short)f2bf(a[0]); v8[1]=(short)f2bf(a[1]); v8[2]=(short)f2bf(a[2]); v8[3]=(short)f2bf(a[3]);
      v8[4]=(short)f2bf(b[0]); v8[5]=(short)f2bf(b[1]); v8[6]=(short)f2bf(b[2]); v8[7]=(short)f2bf(b[3]);
      qfrag[s][kc] = v8;
    }
  }

  // ---- analytic mask regions (wave-uniform per set) ----
  int qreg[3];
#pragma unroll
  for (int s = 0; s < 3; ++s) {
    int t0 = qbase + s * 16;
    int rr_s = t0 >> 5;
    int qh = (wh == 3) ? ((rr_s >= SH) ? 2 : 1) : 0;
    int qw = (ww == 3) ? ((t0 & 16) ? 2 : 1) : 0;
    qreg[s] = qh * 3 + qw;
  }
  const int cw0 = (ww == 3) ? 1 : 0, cw1 = (ww == 3) ? 2 : 0;
  const float MNEG = -144.2695041f;  // -100*log2(e)
  const float SC2 = 0.12751739f;     // log2(e)/sqrt(128)

  floatx4 oacc[3][8];
#pragma unroll
  for (int s = 0; s < 3; ++s)
#pragma unroll
    for (int cb = 0; cb < 8; ++cb) oacc[s][cb] = (floatx4){0.f, 0.f, 0.f, 0.f};
  float lsum[3][4];
#pragma unroll
  for (int s = 0; s < 3; ++s)
#pragma unroll
    for (int r = 0; r < 4; ++r) lsum[s][r] = 0.f;

  // tile 0 staged & visible (tile 1 may still be in flight: vmcnt(4) keeps
  // the 4 newest FIFO entries -- tile 1's chunks -- outstanding)
  asm volatile("s_waitcnt vmcnt(4)" ::: "memory");
  __builtin_amdgcn_s_barrier();

  int cur = 0;
  for (int kt = 0; kt < NKT; ++kt) {
    // issue stage for kt+2 into buffer (kt+2)%3 (== the buffer of kt-1,
    // whose readers all finished before the barrier at bottom of kt-1)
    if (kt + 2 < NKT) {
      int b2 = cur + 2; if (b2 >= 3) b2 -= 3;
      stage(b2, kt + 2);
    }

    // K fragments from LDS (chunk==lane: linear, conflict-free)
    short8 kf0[4], kf1[4];
#pragma unroll
    for (int kc = 0; kc < 4; ++kc) {
      kf0[kc] = *(const short8*)&Kv[cur][kc * 1024 + loff];
      kf1[kc] = *(const short8*)&Kv[cur][kc * 1024 + 512 + loff];
    }

    const int khb = (wh == 3) ? ((kt >= SH) ? 6 : 3) : 0;
    const int kr0 = khb + cw0, kr1 = khb + cw1;

    // ---- QK^T + softmax + packed P write, per set ----
#pragma unroll
    for (int s = 0; s < 3; ++s) {
      floatx4 a0 = (floatx4){0.f, 0.f, 0.f, 0.f};
      floatx4 a1 = (floatx4){0.f, 0.f, 0.f, 0.f};
#pragma unroll
      for (int kc = 0; kc < 4; ++kc) {
        a0 = __builtin_amdgcn_mfma_f32_16x16x32_bf16(qfrag[s][kc], kf0[kc], a0, 0, 0, 0);
        a1 = __builtin_amdgcn_mfma_f32_16x16x32_bf16(qfrag[s][kc], kf1[kc], a1, 0, 0, 0);
      }
      const float m0 = (qreg[s] == kr0) ? 0.f : MNEG;
      const float m1 = (qreg[s] == kr1) ? 0.f : MNEG;
#pragma unroll
      for (int r = 0; r < 4; ++r) {
        float p0 = __builtin_amdgcn_exp2f(fmaf(a0[r], SC2, m0));
        float p1 = __builtin_amdgcn_exp2f(fmaf(a1[r], SC2, m1));
        lsum[s][r] += p0 + p1;
        unsigned pk = (unsigned)f2bf(p0) | ((unsigned)f2bf(p1) << 16);
        *(unsigned*)&Ps[wv][s][(quad * 4 + r) * PSTR + 2 * col] = pk;
      }
    }

    // V fragments from LDS (linear, conflict-free)
    short8 vf[8];
#pragma unroll
    for (int cb = 0; cb < 8; ++cb)
      vf[cb] = *(const short8*)&Kv[cur][4096 + cb * 512 + loff];

    // ---- O += P V (wave-private P, lgkmcnt only) ----
#pragma unroll
    for (int s = 0; s < 3; ++s) {
      short8 pf = *(const short8*)&Ps[wv][s][col * PSTR + quad * 8];
#pragma unroll
      for (int cb = 0; cb < 8; ++cb)
        oacc[s][cb] = __builtin_amdgcn_mfma_f32_16x16x32_bf16(pf, vf[cb], oacc[s][cb], 0, 0, 0);
    }

    // bottom: ensure tile kt+1 landed; never drain to 0 in steady state
    if (kt + 1 < NKT) {
      if (kt + 2 < NKT) asm volatile("s_waitcnt vmcnt(4)" ::: "memory");
      else              asm volatile("s_waitcnt vmcnt(0)" ::: "memory");
      __builtin_amdgcn_s_barrier();
    }
    cur += 1; if (cur == 3) cur = 0;
  }

  // ---- epilogue: reduce l over the 16 cols, divide, store ----
#pragma unroll
  for (int s = 0; s < 3; ++s)
#pragma unroll
    for (int r = 0; r < 4; ++r) {
      float l = lsum[s][r];
      l += __shfl_xor(l, 1); l += __shfl_xor(l, 2);
      l += __shfl_xor(l, 4); l += __shfl_xor(l, 8);
      float inv = 1.0f / l;
      int tok = qbase + s * 16 + quad * 4 + r;
      float* op = out + bbase + (long)tok_off(tok, wh, ww) * C + col;
#pragma unroll
      for (int cb = 0; cb < 8; ++cb) op[cb * 16] = oacc[s][cb][r] * inv;
    }
}

// ---------------- fallback (self-contained, used only if ws too small) -------
#define KSTRF 136
#define VSTRF 40
#define PSTRF 40
__global__ __launch_bounds__(256, 2) void attn_fallback(
    const float* __restrict__ q, const float* __restrict__ k,
    const float* __restrict__ v, const float* __restrict__ mask,
    float* __restrict__ out) {
  __shared__ unsigned short Ks[KT * KSTRF];
  __shared__ unsigned short Vtl[C * VSTRF];
  __shared__ unsigned short Psf[4][16 * PSTRF];
  const int qtile = blockIdx.x;
  const int beta  = blockIdx.y;
  const int batch = beta >> 4;
  const int win   = beta & 15;
  const int wh = win >> 2, ww = win & 3;
  const int tid = threadIdx.x;
  const int wave = tid >> 6, lane = tid & 63;
  const int col = lane & 15, quad = lane >> 4;
  const long bbase = (long)batch * (H * W * C);
  const int qtok = qtile * 64 + wave * 16 + col;
  const float* qp = q + bbase + (long)tok_off(qtok, wh, ww) * C + quad * 8;
  short8 qfrag[4];
#pragma unroll
  for (int kc = 0; kc < 4; ++kc) {
    floatx4 a = *(const floatx4*)(qp + kc * 32);
    floatx4 b = *(const floatx4*)(qp + kc * 32 + 4);
    short8 s;
    s[0]=f2bf(a[0]); s[1]=f2bf(a[1]); s[2]=f2bf(a[2]); s[3]=f2bf(a[3]);
    s[4]=f2bf(b[0]); s[5]=f2bf(b[1]); s[6]=f2bf(b[2]); s[7]=f2bf(b[3]);
    qfrag[kc] = s;
  }
  floatx4 oacc[8];
#pragma unroll
  for (int i = 0; i < 8; ++i) oacc[i] = (floatx4){0.f,0.f,0.f,0.f};
  float mrow[4], lrow[4];
#pragma unroll
  for (int r = 0; r < 4; ++r) { mrow[r] = -1e30f; lrow[r] = 0.f; }
  const int skey = tid >> 3;
  const int sch  = (tid & 7) * 4;
  const float invscale = 0.088388347648318447f;
  const float* maskw = mask + (long)win * (NTOK * NTOK);
  const int qrow_m = qtile * 64 + wave * 16 + quad * 4;
  for (int kt = 0; kt < NKT; ++kt) {
    const int ktok0 = kt * KT;
    const long srow = bbase + (long)tok_off(ktok0 + skey, wh, ww) * C;
    const float* kp = k + srow;
    const float* vp = v + srow;
    __syncthreads();
#pragma unroll
    for (int j = 0; j < 4; ++j) {
      floatx4 f = *(const floatx4*)(kp + sch + j * 32);
      unsigned lo = (unsigned)f2bf(f[0]) | ((unsigned)f2bf(f[1]) << 16);
      unsigned hi = (unsigned)f2bf(f[2]) | ((unsigned)f2bf(f[3]) << 16);
      *(uint2*)&Ks[skey * KSTRF + sch + j * 32] = make_uint2(lo, hi);
    }
#pragma unroll
    for (int j = 0; j < 4; ++j) {
      floatx4 f = *(const floatx4*)(vp + sch + j * 32);
      int chb = sch + j * 32;
      Vtl[(chb + 0) * VSTRF + skey] = f2bf(f[0]);
      Vtl[(chb + 1) * VSTRF + skey] = f2bf(f[1]);
      Vtl[(chb + 2) * VSTRF + skey] = f2bf(f[2]);
      Vtl[(chb + 3) * VSTRF + skey] = f2bf(f[3]);
    }
    __syncthreads();
    floatx4 s0 = (floatx4){0.f,0.f,0.f,0.f};
    floatx4 s1 = (floatx4){0.f,0.f,0.f,0.f};
#pragma unroll
    for (int kc = 0; kc < 4; ++kc) {
      short8 k0 = *(const short8*)&Ks[col * KSTRF + kc * 32 + quad * 8];
      short8 k1 = *(const short8*)&Ks[(col + 16) * KSTRF + kc * 32 + quad * 8];
      s0 = __builtin_amdgcn_mfma_f32_16x16x32_bf16(qfrag[kc], k0, s0, 0, 0, 0);
      s1 = __builtin_amdgcn_mfma_f32_16x16x32_bf16(qfrag[kc], k1, s1, 0, 0, 0);
    }
    float mk0[4], mk1[4];
    const float* mp = maskw + (long)qrow_m * NTOK + ktok0 + col;
#pragma unroll
    for (int r = 0; r < 4; ++r) { mk0[r] = mp[r * NTOK]; mk1[r] = mp[r * NTOK + 16]; }
#pragma unroll
    for (int r = 0; r < 4; ++r) {
      float a0 = s0[r] * invscale + mk0[r];
      float a1 = s1[r] * invscale + mk1[r];
      float mx = fmaxf(a0, a1);
      mx = fmaxf(mx, __shfl_xor(mx, 1)); mx = fmaxf(mx, __shfl_xor(mx, 2));
      mx = fmaxf(mx, __shfl_xor(mx, 4)); mx = fmaxf(mx, __shfl_xor(mx, 8));
      float mnew = fmaxf(mrow[r], mx);
      float alpha = __expf(mrow[r] - mnew);
      float p0 = __expf(a0 - mnew);
      float p1 = __expf(a1 - mnew);
      float rs = p0 + p1;
      rs += __shfl_xor(rs, 1); rs += __shfl_xor(rs, 2);
      rs += __shfl_xor(rs, 4); rs += __shfl_xor(rs, 8);
      lrow[r] = lrow[r] * alpha + rs;
      mrow[r] = mnew;
#pragma unroll
      for (int cb = 0; cb < 8; ++cb) oacc[cb][r] *= alpha;
      Psf[wave][(quad * 4 + r) * PSTRF + col]      = f2bf(p0);
      Psf[wave][(quad * 4 + r) * PSTRF + 16 + col] = f2bf(p1);
    }
    __syncthreads();
    short8 pf = *(const short8*)&Psf[wave][col * PSTRF + quad * 8];
#pragma unroll
    for (int cb = 0; cb < 8; ++cb) {
      short8 vf = *(const short8*)&Vtl[(cb * 16 + col) * VSTRF + quad * 8];
      oacc[cb] = __builtin_amdgcn_mfma_f32_16x16x32_bf16(pf, vf, oacc[cb], 0, 0, 0);
    }
  }
#pragma unroll
  for (int r = 0; r < 4; ++r) {
    float inv_l = 1.0f / lrow[r];
    int tok = qtile * 64 + wave * 16 + quad * 4 + r;
    float* op = out + bbase + (long)tok_off(tok, wh, ww) * C + col;
#pragma unroll
    for (int cb = 0; cb < 8; ++cb) op[cb * 16] = oacc[cb][r] * inv_l;
  }
}

extern "C" void kernel_launch(void* const* d_in, const int* in_sizes, int n_in,
                              void* d_out, int out_size, void* d_ws, size_t ws_size,
                              hipStream_t stream) {
  const float* q    = (const float*)d_in[0];
  const float* k    = (const float*)d_in[1];
  const float* v    = (const float*)d_in[2];
  const float* mask = (const float*)d_in[3];
  float* out = (float*)d_out;
  if (ws_size >= (size_t)WS_NEED) {
    prep_kernel<<<128 * NKT, 256, 0, stream>>>(k, v, (unsigned short*)d_ws);
    attn_main<<<512, 256, 0, stream>>>(q, (const unsigned short*)d_ws, out);
  } else {
    attn_fallback<<<dim3(12, 128), dim3(256), 0, stream>>>(q, k, v, mask, out);
  }
}

// Round 5
// 250.984 us; speedup vs baseline: 1.0132x; 1.0022x over previous
//
#include <hip/hip_runtime.h>

// Problem constants: B=8, H=96, W=128, C=128, NS=4, with_shift=1
#define H 96
#define W 128
#define C 128
#define WSH 24
#define WSW 32
#define NTOK 768
#define SH 12
#define SW 16
#define KT 32        // keys per tile
#define NKT 24       // tiles per window (each tile = one spatial row)
#define PSTR 40      // P LDS row stride (ushorts)
// ws tile: K-frags 8KB + V-frags 8KB. Chunk order v2: within each 1KB region
// (16 keys x 4 quads), chunk index = quad*16+key == lane -> ds_read_b128 at
// byte lane*16 is linear & bank-conflict-free.
#define TILE_USH 8192                  // 16384 B
#define WS_NEED (128L * NKT * TILE_USH * 2)  // 50,331,648 bytes

typedef __attribute__((ext_vector_type(8))) short short8;
typedef __attribute__((ext_vector_type(4))) float floatx4;

__device__ inline unsigned short f2bf(float f) {
  union { float f; unsigned u; } un; un.f = f;
  unsigned r = un.u + 0x7FFF + ((un.u >> 16) & 1);
  return (unsigned short)(r >> 16);
}

// window token -> global spatial offset (y*W + x), folding the shift-roll
__device__ inline int tok_off(int tok, int wh, int ww) {
  int r = tok >> 5;
  int cc = tok & 31;
  int y = wh * WSH + r + SH; if (y >= H) y -= H;
  int x = ww * WSW + cc + SW; if (x >= W) x -= W;
  return y * W + x;
}

// async global->LDS, 16B per lane, LDS dst = wave-uniform base + lane*16
__device__ inline void gll16(const void* g, void* lds) {
  __builtin_amdgcn_global_load_lds(
      (const __attribute__((address_space(1))) unsigned int*)g,
      (__attribute__((address_space(3))) unsigned int*)lds, 16, 0, 0);
}

// ---------------- prep: fp32 K,V -> bf16 MFMA-fragment tiles in ws ----------
// (unchanged from round 4 — passing)
__global__ __launch_bounds__(256) void prep_kernel(const float* __restrict__ k,
                                                   const float* __restrict__ v,
                                                   unsigned short* __restrict__ ws) {
  __shared__ unsigned short Vlds[KT][136];
  const int bid = blockIdx.x;               // 3072 blocks
  const int xcd = bid & 7;
  const int jj = bid >> 3;                  // 0..383
  const int w = xcd * 16 + (jj & 15);       // window 0..127, on XCD w>>4
  const int kt = jj >> 4;                   // 0..23
  const int batch = w >> 4, win = w & 15;
  const int wh = win >> 2, ww = win & 3;
  int y = wh * WSH + kt + SH; if (y >= H) y -= H;

  const int t = threadIdx.x;
  const int key = t >> 3;           // 0..31
  const int j = t & 7;              // channel group of 16
  const int c0 = j * 16;
  int x = ww * WSW + key + SW; if (x >= W) x -= W;
  const long src = ((long)batch * H * W + (long)y * W + x) * C + c0;
  unsigned short* tile = ws + ((long)w * NKT + kt) * TILE_USH;

  // K: convert 16 channels -> two fragment chunks (kc=j>>1, quads 2*(j&1), +1)
  {
    const float* kp = k + src;
    short8 s0, s1;
#pragma unroll
    for (int i = 0; i < 2; ++i) {
      floatx4 a = *(const floatx4*)(kp + i * 8);
      floatx4 b = *(const floatx4*)(kp + i * 8 + 4);
      s0[i*4+0] = (short)f2bf(a[0]); s0[i*4+1] = (short)f2bf(a[1]);
      s0[i*4+2] = (short)f2bf(a[2]); s0[i*4+3] = (short)f2bf(a[3]);
      s1[i*4+0] = (short)f2bf(b[0]); s1[i*4+1] = (short)f2bf(b[1]);
      s1[i*4+2] = (short)f2bf(b[2]); s1[i*4+3] = (short)f2bf(b[3]);
    }
    short8 o0, o1;
    o0[0]=s0[0]; o0[1]=s0[1]; o0[2]=s0[2]; o0[3]=s0[3]; o0[4]=s1[0]; o0[5]=s1[1]; o0[6]=s1[2]; o0[7]=s1[3];
    o1[0]=s0[4]; o1[1]=s0[5]; o1[2]=s0[6]; o1[3]=s0[7]; o1[4]=s1[4]; o1[5]=s1[5]; o1[6]=s1[6]; o1[7]=s1[7];
    const int kc = j >> 1;
    const int q2 = (j & 1) * 2;
    const int half = key >> 4, keyh = key & 15;
    unsigned short* kout = tile + kc * 1024 + half * 512 + keyh * 8;
    *(short8*)(kout + (q2    ) * 128) = o0;   // chunk (q2*16+keyh)
    *(short8*)(kout + (q2 + 1) * 128) = o1;   // chunk ((q2+1)*16+keyh)
  }
  // V: convert into LDS [key][ch]
  {
    const float* vp = v + src;
#pragma unroll
    for (int i = 0; i < 4; ++i) {
      floatx4 a = *(const floatx4*)(vp + i * 4);
      Vlds[key][c0 + i*4 + 0] = f2bf(a[0]);
      Vlds[key][c0 + i*4 + 1] = f2bf(a[1]);
      Vlds[key][c0 + i*4 + 2] = f2bf(a[2]);
      Vlds[key][c0 + i*4 + 3] = f2bf(a[3]);
    }
  }
  __syncthreads();
  // V fragment chunks, permuted key order
  {
    const int cb = t >> 5;
    const int rem = t & 31;
    const int col = rem >> 1, qh = rem & 1;
    const int ch = cb * 16 + col;
#pragma unroll
    for (int qs = 0; qs < 2; ++qs) {
      const int quad = qh * 2 + qs;
      short8 o;
#pragma unroll
      for (int i = 0; i < 8; ++i)
        o[i] = (short)Vlds[(i & 1) * 16 + quad * 4 + (i >> 1)][ch];
      *(short8*)(tile + 4096 + cb * 512 + (quad * 16 + col) * 8) = o;
    }
  }
}

// ---------------- main fused attention ---------------------------------------
// 512 blocks x 256 threads (4 waves). Wave = 48 q-rows (3 sets of 16).
// K/V tile triple-buffered LDS, counted vmcnt (round 4 structure, passing).
// NEW: per-tile loop body is PHASE-GROUPED — [QK all sets] [softmax all sets]
// [P writes] [P reads] [PV all sets] — instead of per-set serial chains.
// Rounds 0-4 showed per-SIMD set throughput invariant (~1180 cyc/set) across
// occupancy x2, K/V global->LDS, conflict-free LDS => bottleneck is the
// per-set dependency chain (QK chain -> exp2 -> P write->read -> PV) which
// the compiler never overlapped across sets (VGPR_Count 128 of 256 budget).
// Phase-grouping exposes 6 parallel QK chains / 24 parallel PV MFMAs / one
// P round-trip per tile. s_setprio around MFMA clusters (T5).
__global__ __launch_bounds__(256, 2) void attn_main(const float* __restrict__ q,
                                                    const unsigned short* __restrict__ ws,
                                                    float* __restrict__ out) {
  __shared__ unsigned short Kv[3][TILE_USH];       // 48 KB triple-buffered
  __shared__ unsigned short Ps[4][3][16 * PSTR];   // 15360 B

  const int bid = blockIdx.x;
  const int x8 = bid & 7;
  const int i = bid >> 3;            // 0..63
  const int w = x8 * 16 + (i & 15);  // window 0..127
  const int qb = i >> 4;             // 0..3 (192 q each)
  const int batch = w >> 4, win = w & 15;
  const int wh = win >> 2, ww = win & 3;

  const int tid = threadIdx.x;
  const int wv = tid >> 6, lane = tid & 63;
  const int col = lane & 15, quad = lane >> 4;
  const long bbase = (long)batch * (H * W * C);
  const int qbase = qb * 192 + wv * 48;
  const int loff = lane * 8;         // fragment chunk offset (ushorts), linear

  const char* wtile = (const char*)(ws + (long)w * (NKT * TILE_USH));

  auto stage = [&](int buf, int kt) {
    const char* g = wtile + ((long)kt << 14);
#pragma unroll
    for (int c = 0; c < 4; ++c) {
      const int chunk = wv * 4 + c;
      gll16(g + chunk * 1024 + lane * 16, &Kv[buf][chunk * 512]);
    }
  };

  stage(0, 0);
  stage(1, 1);   // both overlap with Q prologue below

  // ---- Q fragments: 3 sets x 4 kc, kept in registers ----
  short8 qfrag[3][4];
#pragma unroll
  for (int s = 0; s < 3; ++s) {
    const int qtok = qbase + s * 16 + col;
    const float* qp = q + bbase + (long)tok_off(qtok, wh, ww) * C + quad * 8;
#pragma unroll
    for (int kc = 0; kc < 4; ++kc) {
      floatx4 a = *(const floatx4*)(qp + kc * 32);
      floatx4 b = *(const floatx4*)(qp + kc * 32 + 4);
      short8 v8;
      v8[0]=(short)f2bf(a[0]); v8[1]=(short)f2bf(a[1]); v8[2]=(short)f2bf(a[2]); v8[3]=(short)f2bf(a[3]);
      v8[4]=(short)f2bf(b[0]); v8[5]=(short)f2bf(b[1]); v8[6]=(short)f2bf(b[2]); v8[7]=(short)f2bf(b[3]);
      qfrag[s][kc] = v8;
    }
  }

  // ---- analytic mask regions (wave-uniform per set) ----
  int qreg[3];
#pragma unroll
  for (int s = 0; s < 3; ++s) {
    int t0 = qbase + s * 16;
    int rr_s = t0 >> 5;
    int qh = (wh == 3) ? ((rr_s >= SH) ? 2 : 1) : 0;
    int qw = (ww == 3) ? ((t0 & 16) ? 2 : 1) : 0;
    qreg[s] = qh * 3 + qw;
  }
  const int cw0 = (ww == 3) ? 1 : 0, cw1 = (ww == 3) ? 2 : 0;
  const float MNEG = -144.2695041f;  // -100*log2(e)
  const float SC2 = 0.12751739f;     // log2(e)/sqrt(128)

  floatx4 oacc[3][8];
#pragma unroll
  for (int s = 0; s < 3; ++s)
#pragma unroll
    for (int cb = 0; cb < 8; ++cb) oacc[s][cb] = (floatx4){0.f, 0.f, 0.f, 0.f};
  float lsum[3][4];
#pragma unroll
  for (int s = 0; s < 3; ++s)
#pragma unroll
    for (int r = 0; r < 4; ++r) lsum[s][r] = 0.f;

  // tile 0 staged & visible (tile 1 may still be in flight)
  asm volatile("s_waitcnt vmcnt(4)" ::: "memory");
  __builtin_amdgcn_s_barrier();

  int cur = 0;
  for (int kt = 0; kt < NKT; ++kt) {
    if (kt + 2 < NKT) {
      int b2 = cur + 2; if (b2 >= 3) b2 -= 3;
      stage(b2, kt + 2);
    }

    // K fragments from LDS (chunk==lane: linear, conflict-free)
    short8 kf0[4], kf1[4];
#pragma unroll
    for (int kc = 0; kc < 4; ++kc) {
      kf0[kc] = *(const short8*)&Kv[cur][kc * 1024 + loff];
      kf1[kc] = *(const short8*)&Kv[cur][kc * 1024 + 512 + loff];
    }

    const int khb = (wh == 3) ? ((kt >= SH) ? 6 : 3) : 0;
    const int kr0 = khb + cw0, kr1 = khb + cw1;

    // ---- phase 1: QK^T, ALL sets (6 interleaved MFMA chains) ----
    floatx4 A0[3], A1[3];
#pragma unroll
    for (int s = 0; s < 3; ++s) {
      A0[s] = (floatx4){0.f, 0.f, 0.f, 0.f};
      A1[s] = (floatx4){0.f, 0.f, 0.f, 0.f};
    }
    __builtin_amdgcn_s_setprio(1);
#pragma unroll
    for (int kc = 0; kc < 4; ++kc)
#pragma unroll
      for (int s = 0; s < 3; ++s) {
        A0[s] = __builtin_amdgcn_mfma_f32_16x16x32_bf16(qfrag[s][kc], kf0[kc], A0[s], 0, 0, 0);
        A1[s] = __builtin_amdgcn_mfma_f32_16x16x32_bf16(qfrag[s][kc], kf1[kc], A1[s], 0, 0, 0);
      }
    __builtin_amdgcn_s_setprio(0);

    // V fragment loads issued here: kf regs die above, vf reuses; ~150 cyc of
    // softmax/P-write cover the ds_read latency before PV consumes them.
    short8 vf[8];
#pragma unroll
    for (int cb = 0; cb < 8; ++cb)
      vf[cb] = *(const short8*)&Kv[cur][4096 + cb * 512 + loff];

    // ---- phase 2: softmax, ALL sets, packed P in registers ----
    unsigned pkw[3][4];
#pragma unroll
    for (int s = 0; s < 3; ++s) {
      const float m0 = (qreg[s] == kr0) ? 0.f : MNEG;
      const float m1 = (qreg[s] == kr1) ? 0.f : MNEG;
#pragma unroll
      for (int r = 0; r < 4; ++r) {
        float p0 = __builtin_amdgcn_exp2f(fmaf(A0[s][r], SC2, m0));
        float p1 = __builtin_amdgcn_exp2f(fmaf(A1[s][r], SC2, m1));
        lsum[s][r] += p0 + p1;
        pkw[s][r] = (unsigned)f2bf(p0) | ((unsigned)f2bf(p1) << 16);
      }
    }

    // ---- phase 3: all P writes ----
#pragma unroll
    for (int s = 0; s < 3; ++s)
#pragma unroll
      for (int r = 0; r < 4; ++r)
        *(unsigned*)&Ps[wv][s][(quad * 4 + r) * PSTR + 2 * col] = pkw[s][r];

    // ---- phase 4: all P reads (single lgkm round-trip per tile) ----
    short8 pf[3];
#pragma unroll
    for (int s = 0; s < 3; ++s)
      pf[s] = *(const short8*)&Ps[wv][s][col * PSTR + quad * 8];

    // ---- phase 5: PV, ALL sets (24 independent MFMAs) ----
    __builtin_amdgcn_s_setprio(1);
#pragma unroll
    for (int cb = 0; cb < 8; ++cb)
#pragma unroll
      for (int s = 0; s < 3; ++s)
        oacc[s][cb] = __builtin_amdgcn_mfma_f32_16x16x32_bf16(pf[s], vf[cb], oacc[s][cb], 0, 0, 0);
    __builtin_amdgcn_s_setprio(0);

    // bottom: ensure tile kt+1 landed; never drain to 0 in steady state
    if (kt + 1 < NKT) {
      if (kt + 2 < NKT) asm volatile("s_waitcnt vmcnt(4)" ::: "memory");
      else              asm volatile("s_waitcnt vmcnt(0)" ::: "memory");
      __builtin_amdgcn_s_barrier();
    }
    cur += 1; if (cur == 3) cur = 0;
  }

  // ---- epilogue: reduce l over the 16 cols, divide, store ----
#pragma unroll
  for (int s = 0; s < 3; ++s)
#pragma unroll
    for (int r = 0; r < 4; ++r) {
      float l = lsum[s][r];
      l += __shfl_xor(l, 1); l += __shfl_xor(l, 2);
      l += __shfl_xor(l, 4); l += __shfl_xor(l, 8);
      float inv = 1.0f / l;
      int tok = qbase + s * 16 + quad * 4 + r;
      float* op = out + bbase + (long)tok_off(tok, wh, ww) * C + col;
#pragma unroll
      for (int cb = 0; cb < 8; ++cb) op[cb * 16] = oacc[s][cb][r] * inv;
    }
}

// ---------------- fallback (self-contained, used only if ws too small) -------
#define KSTRF 136
#define VSTRF 40
#define PSTRF 40
__global__ __launch_bounds__(256, 2) void attn_fallback(
    const float* __restrict__ q, const float* __restrict__ k,
    const float* __restrict__ v, const float* __restrict__ mask,
    float* __restrict__ out) {
  __shared__ unsigned short Ks[KT * KSTRF];
  __shared__ unsigned short Vtl[C * VSTRF];
  __shared__ unsigned short Psf[4][16 * PSTRF];
  const int qtile = blockIdx.x;
  const int beta  = blockIdx.y;
  const int batch = beta >> 4;
  const int win   = beta & 15;
  const int wh = win >> 2, ww = win & 3;
  const int tid = threadIdx.x;
  const int wave = tid >> 6, lane = tid & 63;
  const int col = lane & 15, quad = lane >> 4;
  const long bbase = (long)batch * (H * W * C);
  const int qtok = qtile * 64 + wave * 16 + col;
  const float* qp = q + bbase + (long)tok_off(qtok, wh, ww) * C + quad * 8;
  short8 qfrag[4];
#pragma unroll
  for (int kc = 0; kc < 4; ++kc) {
    floatx4 a = *(const floatx4*)(qp + kc * 32);
    floatx4 b = *(const floatx4*)(qp + kc * 32 + 4);
    short8 s;
    s[0]=f2bf(a[0]); s[1]=f2bf(a[1]); s[2]=f2bf(a[2]); s[3]=f2bf(a[3]);
    s[4]=f2bf(b[0]); s[5]=f2bf(b[1]); s[6]=f2bf(b[2]); s[7]=f2bf(b[3]);
    qfrag[kc] = s;
  }
  floatx4 oacc[8];
#pragma unroll
  for (int i = 0; i < 8; ++i) oacc[i] = (floatx4){0.f,0.f,0.f,0.f};
  float mrow[4], lrow[4];
#pragma unroll
  for (int r = 0; r < 4; ++r) { mrow[r] = -1e30f; lrow[r] = 0.f; }
  const int skey = tid >> 3;
  const int sch  = (tid & 7) * 4;
  const float invscale = 0.088388347648318447f;
  const float* maskw = mask + (long)win * (NTOK * NTOK);
  const int qrow_m = qtile * 64 + wave * 16 + quad * 4;
  for (int kt = 0; kt < NKT; ++kt) {
    const int ktok0 = kt * KT;
    const long srow = bbase + (long)tok_off(ktok0 + skey, wh, ww) * C;
    const float* kp = k + srow;
    const float* vp = v + srow;
    __syncthreads();
#pragma unroll
    for (int j = 0; j < 4; ++j) {
      floatx4 f = *(const floatx4*)(kp + sch + j * 32);
      unsigned lo = (unsigned)f2bf(f[0]) | ((unsigned)f2bf(f[1]) << 16);
      unsigned hi = (unsigned)f2bf(f[2]) | ((unsigned)f2bf(f[3]) << 16);
      *(uint2*)&Ks[skey * KSTRF + sch + j * 32] = make_uint2(lo, hi);
    }
#pragma unroll
    for (int j = 0; j < 4; ++j) {
      floatx4 f = *(const floatx4*)(vp + sch + j * 32);
      int chb = sch + j * 32;
      Vtl[(chb + 0) * VSTRF + skey] = f2bf(f[0]);
      Vtl[(chb + 1) * VSTRF + skey] = f2bf(f[1]);
      Vtl[(chb + 2) * VSTRF + skey] = f2bf(f[2]);
      Vtl[(chb + 3) * VSTRF + skey] = f2bf(f[3]);
    }
    __syncthreads();
    floatx4 s0 = (floatx4){0.f,0.f,0.f,0.f};
    floatx4 s1 = (floatx4){0.f,0.f,0.f,0.f};
#pragma unroll
    for (int kc = 0; kc < 4; ++kc) {
      short8 k0 = *(const short8*)&Ks[col * KSTRF + kc * 32 + quad * 8];
      short8 k1 = *(const short8*)&Ks[(col + 16) * KSTRF + kc * 32 + quad * 8];
      s0 = __builtin_amdgcn_mfma_f32_16x16x32_bf16(qfrag[kc], k0, s0, 0, 0, 0);
      s1 = __builtin_amdgcn_mfma_f32_16x16x32_bf16(qfrag[kc], k1, s1, 0, 0, 0);
    }
    float mk0[4], mk1[4];
    const float* mp = maskw + (long)qrow_m * NTOK + ktok0 + col;
#pragma unroll
    for (int r = 0; r < 4; ++r) { mk0[r] = mp[r * NTOK]; mk1[r] = mp[r * NTOK + 16]; }
#pragma unroll
    for (int r = 0; r < 4; ++r) {
      float a0 = s0[r] * invscale + mk0[r];
      float a1 = s1[r] * invscale + mk1[r];
      float mx = fmaxf(a0, a1);
      mx = fmaxf(mx, __shfl_xor(mx, 1)); mx = fmaxf(mx, __shfl_xor(mx, 2));
      mx = fmaxf(mx, __shfl_xor(mx, 4)); mx = fmaxf(mx, __shfl_xor(mx, 8));
      float mnew = fmaxf(mrow[r], mx);
      float alpha = __expf(mrow[r] - mnew);
      float p0 = __expf(a0 - mnew);
      float p1 = __expf(a1 - mnew);
      float rs = p0 + p1;
      rs += __shfl_xor(rs, 1); rs += __shfl_xor(rs, 2);
      rs += __shfl_xor(rs, 4); rs += __shfl_xor(rs, 8);
      lrow[r] = lrow[r] * alpha + rs;
      mrow[r] = mnew;
#pragma unroll
      for (int cb = 0; cb < 8; ++cb) oacc[cb][r] *= alpha;
      Psf[wave][(quad * 4 + r) * PSTRF + col]      = f2bf(p0);
      Psf[wave][(quad * 4 + r) * PSTRF + 16 + col] = f2bf(p1);
    }
    __syncthreads();
    short8 pf = *(const short8*)&Psf[wave][col * PSTRF + quad * 8];
#pragma unroll
    for (int cb = 0; cb < 8; ++cb) {
      short8 vf = *(const short8*)&Vtl[(cb * 16 + col) * VSTRF + quad * 8];
      oacc[cb] = __builtin_amdgcn_mfma_f32_16x16x32_bf16(pf, vf, oacc[cb], 0, 0, 0);
    }
  }
#pragma unroll
  for (int r = 0; r < 4; ++r) {
    float inv_l = 1.0f / lrow[r];
    int tok = qtile * 64 + wave * 16 + quad * 4 + r;
    float* op = out + bbase + (long)tok_off(tok, wh, ww) * C + col;
#pragma unroll
    for (int cb = 0; cb < 8; ++cb) op[cb * 16] = oacc[cb][r] * inv_l;
  }
}

extern "C" void kernel_launch(void* const* d_in, const int* in_sizes, int n_in,
                              void* d_out, int out_size, void* d_ws, size_t ws_size,
                              hipStream_t stream) {
  const float* q    = (const float*)d_in[0];
  const float* k    = (const float*)d_in[1];
  const float* v    = (const float*)d_in[2];
  const float* mask = (const float*)d_in[3];
  float* out = (float*)d_out;
  if (ws_size >= (size_t)WS_NEED) {
    prep_kernel<<<128 * NKT, 256, 0, stream>>>(k, v, (unsigned short*)d_ws);
    attn_main<<<512, 256, 0, stream>>>(q, (const unsigned short*)d_ws, out);
  } else {
    attn_fallback<<<dim3(12, 128), dim3(256), 0, stream>>>(q, k, v, mask, out);
  }
}

// Round 6
// 248.159 us; speedup vs baseline: 1.0247x; 1.0114x over previous
//
#include <hip/hip_runtime.h>

// Problem constants: B=8, H=96, W=128, C=128, NS=4, with_shift=1
#define H 96
#define W 128
#define C 128
#define WSH 24
#define WSW 32
#define NTOK 768
#define SH 12
#define SW 16
#define KT 32        // keys per tile
#define NKT 24       // tiles per window (each tile = one spatial row)
#define PSTR 40      // P LDS row stride (ushorts)
// ws tile: K-frags 8KB + V-frags 8KB, chunk index == lane (conflict-free b128)
#define TILE_USH 8192                  // 16384 B
#define WS_NEED (128L * NKT * TILE_USH * 2)  // 50,331,648 bytes

typedef __attribute__((ext_vector_type(8))) short short8;
typedef __attribute__((ext_vector_type(4))) float floatx4;

__device__ inline unsigned short f2bf(float f) {
  union { float f; unsigned u; } un; un.f = f;
  unsigned r = un.u + 0x7FFF + ((un.u >> 16) & 1);
  return (unsigned short)(r >> 16);
}

// window token -> global spatial offset (y*W + x), folding the shift-roll
__device__ inline int tok_off(int tok, int wh, int ww) {
  int r = tok >> 5;
  int cc = tok & 31;
  int y = wh * WSH + r + SH; if (y >= H) y -= H;
  int x = ww * WSW + cc + SW; if (x >= W) x -= W;
  return y * W + x;
}

// async global->LDS, 16B per lane, LDS dst = wave-uniform base + lane*16
__device__ inline void gll16(const void* g, void* lds) {
  __builtin_amdgcn_global_load_lds(
      (const __attribute__((address_space(1))) unsigned int*)g,
      (__attribute__((address_space(3))) unsigned int*)lds, 16, 0, 0);
}

// ---------------- prep: fp32 K,V -> bf16 MFMA-fragment tiles in ws ----------
// (round-4 structure, passing; Vlds writes now u32-packed: half the scalar
// LDS stores)
__global__ __launch_bounds__(256) void prep_kernel(const float* __restrict__ k,
                                                   const float* __restrict__ v,
                                                   unsigned short* __restrict__ ws) {
  __shared__ unsigned short Vlds[KT][136];
  const int bid = blockIdx.x;               // 3072 blocks
  const int xcd = bid & 7;
  const int jj = bid >> 3;                  // 0..383
  const int w = xcd * 16 + (jj & 15);       // window 0..127, on XCD w>>4
  const int kt = jj >> 4;                   // 0..23
  const int batch = w >> 4, win = w & 15;
  const int wh = win >> 2, ww = win & 3;
  int y = wh * WSH + kt + SH; if (y >= H) y -= H;

  const int t = threadIdx.x;
  const int key = t >> 3;           // 0..31
  const int j = t & 7;              // channel group of 16
  const int c0 = j * 16;
  int x = ww * WSW + key + SW; if (x >= W) x -= W;
  const long src = ((long)batch * H * W + (long)y * W + x) * C + c0;
  unsigned short* tile = ws + ((long)w * NKT + kt) * TILE_USH;

  // K: convert 16 channels -> two fragment chunks
  {
    const float* kp = k + src;
    short8 s0, s1;
#pragma unroll
    for (int i = 0; i < 2; ++i) {
      floatx4 a = *(const floatx4*)(kp + i * 8);
      floatx4 b = *(const floatx4*)(kp + i * 8 + 4);
      s0[i*4+0] = (short)f2bf(a[0]); s0[i*4+1] = (short)f2bf(a[1]);
      s0[i*4+2] = (short)f2bf(a[2]); s0[i*4+3] = (short)f2bf(a[3]);
      s1[i*4+0] = (short)f2bf(b[0]); s1[i*4+1] = (short)f2bf(b[1]);
      s1[i*4+2] = (short)f2bf(b[2]); s1[i*4+3] = (short)f2bf(b[3]);
    }
    short8 o0, o1;
    o0[0]=s0[0]; o0[1]=s0[1]; o0[2]=s0[2]; o0[3]=s0[3]; o0[4]=s1[0]; o0[5]=s1[1]; o0[6]=s1[2]; o0[7]=s1[3];
    o1[0]=s0[4]; o1[1]=s0[5]; o1[2]=s0[6]; o1[3]=s0[7]; o1[4]=s1[4]; o1[5]=s1[5]; o1[6]=s1[6]; o1[7]=s1[7];
    const int kc = j >> 1;
    const int q2 = (j & 1) * 2;
    const int half = key >> 4, keyh = key & 15;
    unsigned short* kout = tile + kc * 1024 + half * 512 + keyh * 8;
    *(short8*)(kout + (q2    ) * 128) = o0;   // chunk (q2*16+keyh)
    *(short8*)(kout + (q2 + 1) * 128) = o1;   // chunk ((q2+1)*16+keyh)
  }
  // V: convert into LDS [key][ch], u32-packed writes
  {
    const float* vp = v + src;
#pragma unroll
    for (int i = 0; i < 4; ++i) {
      floatx4 a = *(const floatx4*)(vp + i * 4);
      unsigned lo = (unsigned)f2bf(a[0]) | ((unsigned)f2bf(a[1]) << 16);
      unsigned hi = (unsigned)f2bf(a[2]) | ((unsigned)f2bf(a[3]) << 16);
      *(unsigned*)&Vlds[key][c0 + i*4]     = lo;
      *(unsigned*)&Vlds[key][c0 + i*4 + 2] = hi;
    }
  }
  __syncthreads();
  // V fragment chunks, permuted key order
  {
    const int cb = t >> 5;
    const int rem = t & 31;
    const int col = rem >> 1, qh = rem & 1;
    const int ch = cb * 16 + col;
#pragma unroll
    for (int qs = 0; qs < 2; ++qs) {
      const int quad = qh * 2 + qs;
      short8 o;
#pragma unroll
      for (int i = 0; i < 8; ++i)
        o[i] = (short)Vlds[(i & 1) * 16 + quad * 4 + (i >> 1)][ch];
      *(short8*)(tile + 4096 + cb * 512 + (quad * 16 + col) * 8) = o;
    }
  }
}

// ---------------- main fused attention ---------------------------------------
// 512 blocks x 256 threads (4 waves). Wave = 48 q-rows (3 sets of 16).
// STRUCTURAL software pipeline across tiles: iteration kt executes
//   [PV(kt-1) from carried pf/vf] [stage(kt+2)] [QK+SM+Pwrite(kt)] [Vload(kt)]
//   [lgkmcnt(0)+vmcnt(N)+barrier]
// P/V state is LIVE ACROSS the barrier -> the register allocator CANNOT
// re-serialize the pipeline (rounds 0-5 all compiled to the same per-set
// serial chain at VGPR=128; r5's phase grouping was silently undone). The
// P write->read LDS latency is now hidden under a full barrier interval and
// PV is a 24-wide independent MFMA burst. lgkmcnt(0) before each barrier
// makes the buffer-overwrite by next iteration's stage race-free.
__global__ __launch_bounds__(256, 2) void attn_main(const float* __restrict__ q,
                                                    const unsigned short* __restrict__ ws,
                                                    float* __restrict__ out) {
  __shared__ unsigned short Kv[3][TILE_USH];       // 48 KB triple-buffered
  __shared__ unsigned short Ps[4][3][16 * PSTR];   // 15360 B

  const int bid = blockIdx.x;
  const int x8 = bid & 7;
  const int i = bid >> 3;            // 0..63
  const int w = x8 * 16 + (i & 15);  // window 0..127 (XCD-matched to prep)
  const int qb = i >> 4;             // 0..3 (192 q each)
  const int batch = w >> 4, win = w & 15;
  const int wh = win >> 2, ww = win & 3;

  const int tid = threadIdx.x;
  const int wv = tid >> 6, lane = tid & 63;
  const int col = lane & 15, quad = lane >> 4;
  const long bbase = (long)batch * (H * W * C);
  const int qbase = qb * 192 + wv * 48;
  const int loff = lane * 8;         // fragment chunk offset (ushorts), linear

  const char* wtile = (const char*)(ws + (long)w * (NKT * TILE_USH));

  auto stage = [&](int buf, int kt) {
    const char* g = wtile + ((long)kt << 14);
#pragma unroll
    for (int c = 0; c < 4; ++c) {
      const int chunk = wv * 4 + c;
      gll16(g + chunk * 1024 + lane * 16, &Kv[buf][chunk * 512]);
    }
  };

  stage(0, 0); stage(1, 1); stage(2, 2);   // fill all 3 buffers up front

  // ---- Q fragments: 3 sets x 4 kc, kept in registers ----
  short8 qfrag[3][4];
#pragma unroll
  for (int s = 0; s < 3; ++s) {
    const int qtok = qbase + s * 16 + col;
    const float* qp = q + bbase + (long)tok_off(qtok, wh, ww) * C + quad * 8;
#pragma unroll
    for (int kc = 0; kc < 4; ++kc) {
      floatx4 a = *(const floatx4*)(qp + kc * 32);
      floatx4 b = *(const floatx4*)(qp + kc * 32 + 4);
      short8 v8;
      v8[0]=(short)f2bf(a[0]); v8[1]=(short)f2bf(a[1]); v8[2]=(short)f2bf(a[2]); v8[3]=(short)f2bf(a[3]);
      v8[4]=(short)f2bf(b[0]); v8[5]=(short)f2bf(b[1]); v8[6]=(short)f2bf(b[2]); v8[7]=(short)f2bf(b[3]);
      qfrag[s][kc] = v8;
    }
  }

  // ---- analytic mask regions (wave-uniform per set) ----
  int qreg[3];
#pragma unroll
  for (int s = 0; s < 3; ++s) {
    int t0 = qbase + s * 16;
    int rr_s = t0 >> 5;
    int qh = (wh == 3) ? ((rr_s >= SH) ? 2 : 1) : 0;
    int qw = (ww == 3) ? ((t0 & 16) ? 2 : 1) : 0;
    qreg[s] = qh * 3 + qw;
  }
  const int cw0 = (ww == 3) ? 1 : 0, cw1 = (ww == 3) ? 2 : 0;
  const float MNEG = -144.2695041f;  // -100*log2(e)
  const float SC2 = 0.12751739f;     // log2(e)/sqrt(128)

  floatx4 oacc[3][8];
#pragma unroll
  for (int s = 0; s < 3; ++s)
#pragma unroll
    for (int cb = 0; cb < 8; ++cb) oacc[s][cb] = (floatx4){0.f, 0.f, 0.f, 0.f};
  float lsum[3][4];
#pragma unroll
  for (int s = 0; s < 3; ++s)
#pragma unroll
    for (int r = 0; r < 4; ++r) lsum[s][r] = 0.f;

  // QK + softmax + P-write for tile kt from buffer buf
  auto qk_sm_pw = [&](int kt, int buf) {
    short8 kf0[4], kf1[4];
#pragma unroll
    for (int kc = 0; kc < 4; ++kc) {
      kf0[kc] = *(const short8*)&Kv[buf][kc * 1024 + loff];
      kf1[kc] = *(const short8*)&Kv[buf][kc * 1024 + 512 + loff];
    }
    const int khb = (wh == 3) ? ((kt >= SH) ? 6 : 3) : 0;
    const int kr0 = khb + cw0, kr1 = khb + cw1;

    floatx4 A0[3], A1[3];
#pragma unroll
    for (int s = 0; s < 3; ++s) {
      A0[s] = (floatx4){0.f, 0.f, 0.f, 0.f};
      A1[s] = (floatx4){0.f, 0.f, 0.f, 0.f};
    }
    __builtin_amdgcn_s_setprio(1);
#pragma unroll
    for (int kc = 0; kc < 4; ++kc)
#pragma unroll
      for (int s = 0; s < 3; ++s) {
        A0[s] = __builtin_amdgcn_mfma_f32_16x16x32_bf16(qfrag[s][kc], kf0[kc], A0[s], 0, 0, 0);
        A1[s] = __builtin_amdgcn_mfma_f32_16x16x32_bf16(qfrag[s][kc], kf1[kc], A1[s], 0, 0, 0);
      }
    __builtin_amdgcn_s_setprio(0);

#pragma unroll
    for (int s = 0; s < 3; ++s) {
      const float m0 = (qreg[s] == kr0) ? 0.f : MNEG;
      const float m1 = (qreg[s] == kr1) ? 0.f : MNEG;
#pragma unroll
      for (int r = 0; r < 4; ++r) {
        float p0 = __builtin_amdgcn_exp2f(fmaf(A0[s][r], SC2, m0));
        float p1 = __builtin_amdgcn_exp2f(fmaf(A1[s][r], SC2, m1));
        lsum[s][r] += p0 + p1;
        unsigned pk = (unsigned)f2bf(p0) | ((unsigned)f2bf(p1) << 16);
        *(unsigned*)&Ps[wv][s][(quad * 4 + r) * PSTR + 2 * col] = pk;
      }
    }
  };

  // PV for the tile whose P is in Ps and whose V is in vf regs
  short8 vf[8];
  auto loadV = [&](int buf) {
#pragma unroll
    for (int cb = 0; cb < 8; ++cb)
      vf[cb] = *(const short8*)&Kv[buf][4096 + cb * 512 + loff];
  };
  auto pv = [&]() {
    short8 pf[3];
#pragma unroll
    for (int s = 0; s < 3; ++s)
      pf[s] = *(const short8*)&Ps[wv][s][col * PSTR + quad * 8];
    __builtin_amdgcn_s_setprio(1);
#pragma unroll
    for (int cb = 0; cb < 8; ++cb)
#pragma unroll
      for (int s = 0; s < 3; ++s)
        oacc[s][cb] = __builtin_amdgcn_mfma_f32_16x16x32_bf16(pf[s], vf[cb], oacc[s][cb], 0, 0, 0);
    __builtin_amdgcn_s_setprio(0);
  };

  // tile 0 staged (Q loads drained by their own consumers above)
  asm volatile("s_waitcnt vmcnt(8)" ::: "memory");
  __builtin_amdgcn_s_barrier();

  // ---- peel tile 0: QK/SM/Pwrite + V load; no PV yet ----
  qk_sm_pw(0, 0);
  loadV(0);
  asm volatile("s_waitcnt vmcnt(4) lgkmcnt(0)" ::: "memory");  // tiles 0,1 landed; V reads done
  __builtin_amdgcn_s_barrier();

  for (int kt = 1; kt < NKT; ++kt) {
    const int buf = kt % 3;
    // stage kt+2 into buf[(kt+2)%3] == buffer of kt-1 (all reads drained at
    // the lgkmcnt(0)+barrier above)
    if (kt + 2 < NKT) stage((kt + 2) % 3, kt + 2);

    pv();                 // PV(kt-1): carried pf/vf, independent MFMA burst
    qk_sm_pw(kt, buf);    // serial chain of this tile
    loadV(buf);           // V(kt) into carried regs, consumed next iteration

    if (kt + 1 < NKT) {
      if (kt + 2 < NKT) asm volatile("s_waitcnt vmcnt(4) lgkmcnt(0)" ::: "memory");
      else              asm volatile("s_waitcnt vmcnt(0) lgkmcnt(0)" ::: "memory");
      __builtin_amdgcn_s_barrier();
    }
  }
  pv();   // tail: PV(NKT-1)

  // ---- epilogue: reduce l over the 16 cols, divide, store ----
#pragma unroll
  for (int s = 0; s < 3; ++s)
#pragma unroll
    for (int r = 0; r < 4; ++r) {
      float l = lsum[s][r];
      l += __shfl_xor(l, 1); l += __shfl_xor(l, 2);
      l += __shfl_xor(l, 4); l += __shfl_xor(l, 8);
      float inv = 1.0f / l;
      int tok = qbase + s * 16 + quad * 4 + r;
      float* op = out + bbase + (long)tok_off(tok, wh, ww) * C + col;
#pragma unroll
      for (int cb = 0; cb < 8; ++cb) op[cb * 16] = oacc[s][cb][r] * inv;
    }
}

// ---------------- fallback (self-contained, used only if ws too small) -------
#define KSTRF 136
#define VSTRF 40
#define PSTRF 40
__global__ __launch_bounds__(256, 2) void attn_fallback(
    const float* __restrict__ q, const float* __restrict__ k,
    const float* __restrict__ v, const float* __restrict__ mask,
    float* __restrict__ out) {
  __shared__ unsigned short Ks[KT * KSTRF];
  __shared__ unsigned short Vtl[C * VSTRF];
  __shared__ unsigned short Psf[4][16 * PSTRF];
  const int qtile = blockIdx.x;
  const int beta  = blockIdx.y;
  const int batch = beta >> 4;
  const int win   = beta & 15;
  const int wh = win >> 2, ww = win & 3;
  const int tid = threadIdx.x;
  const int wave = tid >> 6, lane = tid & 63;
  const int col = lane & 15, quad = lane >> 4;
  const long bbase = (long)batch * (H * W * C);
  const int qtok = qtile * 64 + wave * 16 + col;
  const float* qp = q + bbase + (long)tok_off(qtok, wh, ww) * C + quad * 8;
  short8 qfrag[4];
#pragma unroll
  for (int kc = 0; kc < 4; ++kc) {
    floatx4 a = *(const floatx4*)(qp + kc * 32);
    floatx4 b = *(const floatx4*)(qp + kc * 32 + 4);
    short8 s;
    s[0]=f2bf(a[0]); s[1]=f2bf(a[1]); s[2]=f2bf(a[2]); s[3]=f2bf(a[3]);
    s[4]=f2bf(b[0]); s[5]=f2bf(b[1]); s[6]=f2bf(b[2]); s[7]=f2bf(b[3]);
    qfrag[kc] = s;
  }
  floatx4 oacc[8];
#pragma unroll
  for (int i = 0; i < 8; ++i) oacc[i] = (floatx4){0.f,0.f,0.f,0.f};
  float mrow[4], lrow[4];
#pragma unroll
  for (int r = 0; r < 4; ++r) { mrow[r] = -1e30f; lrow[r] = 0.f; }
  const int skey = tid >> 3;
  const int sch  = (tid & 7) * 4;
  const float invscale = 0.088388347648318447f;
  const float* maskw = mask + (long)win * (NTOK * NTOK);
  const int qrow_m = qtile * 64 + wave * 16 + quad * 4;
  for (int kt = 0; kt < NKT; ++kt) {
    const int ktok0 = kt * KT;
    const long srow = bbase + (long)tok_off(ktok0 + skey, wh, ww) * C;
    const float* kp = k + srow;
    const float* vp = v + srow;
    __syncthreads();
#pragma unroll
    for (int j = 0; j < 4; ++j) {
      floatx4 f = *(const floatx4*)(kp + sch + j * 32);
      unsigned lo = (unsigned)f2bf(f[0]) | ((unsigned)f2bf(f[1]) << 16);
      unsigned hi = (unsigned)f2bf(f[2]) | ((unsigned)f2bf(f[3]) << 16);
      *(uint2*)&Ks[skey * KSTRF + sch + j * 32] = make_uint2(lo, hi);
    }
#pragma unroll
    for (int j = 0; j < 4; ++j) {
      floatx4 f = *(const floatx4*)(vp + sch + j * 32);
      int chb = sch + j * 32;
      Vtl[(chb + 0) * VSTRF + skey] = f2bf(f[0]);
      Vtl[(chb + 1) * VSTRF + skey] = f2bf(f[1]);
      Vtl[(chb + 2) * VSTRF + skey] = f2bf(f[2]);
      Vtl[(chb + 3) * VSTRF + skey] = f2bf(f[3]);
    }
    __syncthreads();
    floatx4 s0 = (floatx4){0.f,0.f,0.f,0.f};
    floatx4 s1 = (floatx4){0.f,0.f,0.f,0.f};
#pragma unroll
    for (int kc = 0; kc < 4; ++kc) {
      short8 k0 = *(const short8*)&Ks[col * KSTRF + kc * 32 + quad * 8];
      short8 k1 = *(const short8*)&Ks[(col + 16) * KSTRF + kc * 32 + quad * 8];
      s0 = __builtin_amdgcn_mfma_f32_16x16x32_bf16(qfrag[kc], k0, s0, 0, 0, 0);
      s1 = __builtin_amdgcn_mfma_f32_16x16x32_bf16(qfrag[kc], k1, s1, 0, 0, 0);
    }
    float mk0[4], mk1[4];
    const float* mp = maskw + (long)qrow_m * NTOK + ktok0 + col;
#pragma unroll
    for (int r = 0; r < 4; ++r) { mk0[r] = mp[r * NTOK]; mk1[r] = mp[r * NTOK + 16]; }
#pragma unroll
    for (int r = 0; r < 4; ++r) {
      float a0 = s0[r] * invscale + mk0[r];
      float a1 = s1[r] * invscale + mk1[r];
      float mx = fmaxf(a0, a1);
      mx = fmaxf(mx, __shfl_xor(mx, 1)); mx = fmaxf(mx, __shfl_xor(mx, 2));
      mx = fmaxf(mx, __shfl_xor(mx, 4)); mx = fmaxf(mx, __shfl_xor(mx, 8));
      float mnew = fmaxf(mrow[r], mx);
      float alpha = __expf(mrow[r] - mnew);
      float p0 = __expf(a0 - mnew);
      float p1 = __expf(a1 - mnew);
      float rs = p0 + p1;
      rs += __shfl_xor(rs, 1); rs += __shfl_xor(rs, 2);
      rs += __shfl_xor(rs, 4); rs += __shfl_xor(rs, 8);
      lrow[r] = lrow[r] * alpha + rs;
      mrow[r] = mnew;
#pragma unroll
      for (int cb = 0; cb < 8; ++cb) oacc[cb][r] *= alpha;
      Psf[wave][(quad * 4 + r) * PSTRF + col]      = f2bf(p0);
      Psf[wave][(quad * 4 + r) * PSTRF + 16 + col] = f2bf(p1);
    }
    __syncthreads();
    short8 pf = *(const short8*)&Psf[wave][col * PSTRF + quad * 8];
#pragma unroll
    for (int cb = 0; cb < 8; ++cb) {
      short8 vf = *(const short8*)&Vtl[(cb * 16 + col) * VSTRF + quad * 8];
      oacc[cb] = __builtin_amdgcn_mfma_f32_16x16x32_bf16(pf, vf, oacc[cb], 0, 0, 0);
    }
  }
#pragma unroll
  for (int r = 0; r < 4; ++r) {
    float inv_l = 1.0f / lrow[r];
    int tok = qtile * 64 + wave * 16 + quad * 4 + r;
    float* op = out + bbase + (long)tok_off(tok, wh, ww) * C + col;
#pragma unroll
    for (int cb = 0; cb < 8; ++cb) op[cb * 16] = oacc[cb][r] * inv_l;
  }
}

extern "C" void kernel_launch(void* const* d_in, const int* in_sizes, int n_in,
                              void* d_out, int out_size, void* d_ws, size_t ws_size,
                              hipStream_t stream) {
  const float* q    = (const float*)d_in[0];
  const float* k    = (const float*)d_in[1];
  const float* v    = (const float*)d_in[2];
  const float* mask = (const float*)d_in[3];
  float* out = (float*)d_out;
  if (ws_size >= (size_t)WS_NEED) {
    prep_kernel<<<128 * NKT, 256, 0, stream>>>(k, v, (unsigned short*)d_ws);
    attn_main<<<512, 256, 0, stream>>>(q, (const unsigned short*)d_ws, out);
  } else {
    attn_fallback<<<dim3(12, 128), dim3(256), 0, stream>>>(q, k, v, mask, out);
  }
}

// Round 7
// 246.673 us; speedup vs baseline: 1.0309x; 1.0060x over previous
//
#include <hip/hip_runtime.h>

// Problem constants: B=8, H=96, W=128, C=128, NS=4, with_shift=1
#define H 96
#define W 128
#define C 128
#define WSH 24
#define WSW 32
#define NTOK 768
#define SH 12
#define SW 16
#define KT 32        // keys per tile
#define NKT 24       // tiles per window (each tile = one spatial row)
// ws tile: K-frags 8KB + V-frags 8KB, chunk index == lane (conflict-free b128)
#define TILE_USH 8192                  // 16384 B
#define WS_NEED (128L * NKT * TILE_USH * 2)  // 50,331,648 bytes

typedef __attribute__((ext_vector_type(8))) short short8;
typedef __attribute__((ext_vector_type(4))) float floatx4;

union U8 { short8 s8; unsigned u[4]; };

__device__ inline unsigned short f2bf(float f) {
  union { float f; unsigned u; } un; un.f = f;
  unsigned r = un.u + 0x7FFF + ((un.u >> 16) & 1);
  return (unsigned short)(r >> 16);
}

// window token -> global spatial offset (y*W + x), folding the shift-roll
__device__ inline int tok_off(int tok, int wh, int ww) {
  int r = tok >> 5;
  int cc = tok & 31;
  int y = wh * WSH + r + SH; if (y >= H) y -= H;
  int x = ww * WSW + cc + SW; if (x >= W) x -= W;
  return y * W + x;
}

// async global->LDS, 16B per lane, LDS dst = wave-uniform base + lane*16
__device__ inline void gll16(const void* g, void* lds) {
  __builtin_amdgcn_global_load_lds(
      (const __attribute__((address_space(1))) unsigned int*)g,
      (__attribute__((address_space(3))) unsigned int*)lds, 16, 0, 0);
}

// ---------------- prep: fp32 K,V -> bf16 MFMA-fragment tiles in ws ----------
// (unchanged from round 6 — passing)
__global__ __launch_bounds__(256) void prep_kernel(const float* __restrict__ k,
                                                   const float* __restrict__ v,
                                                   unsigned short* __restrict__ ws) {
  __shared__ unsigned short Vlds[KT][136];
  const int bid = blockIdx.x;               // 3072 blocks
  const int xcd = bid & 7;
  const int jj = bid >> 3;                  // 0..383
  const int w = xcd * 16 + (jj & 15);       // window 0..127, on XCD w>>4
  const int kt = jj >> 4;                   // 0..23
  const int batch = w >> 4, win = w & 15;
  const int wh = win >> 2, ww = win & 3;
  int y = wh * WSH + kt + SH; if (y >= H) y -= H;

  const int t = threadIdx.x;
  const int key = t >> 3;           // 0..31
  const int j = t & 7;              // channel group of 16
  const int c0 = j * 16;
  int x = ww * WSW + key + SW; if (x >= W) x -= W;
  const long src = ((long)batch * H * W + (long)y * W + x) * C + c0;
  unsigned short* tile = ws + ((long)w * NKT + kt) * TILE_USH;

  // K: convert 16 channels -> two fragment chunks
  {
    const float* kp = k + src;
    short8 s0, s1;
#pragma unroll
    for (int i = 0; i < 2; ++i) {
      floatx4 a = *(const floatx4*)(kp + i * 8);
      floatx4 b = *(const floatx4*)(kp + i * 8 + 4);
      s0[i*4+0] = (short)f2bf(a[0]); s0[i*4+1] = (short)f2bf(a[1]);
      s0[i*4+2] = (short)f2bf(a[2]); s0[i*4+3] = (short)f2bf(a[3]);
      s1[i*4+0] = (short)f2bf(b[0]); s1[i*4+1] = (short)f2bf(b[1]);
      s1[i*4+2] = (short)f2bf(b[2]); s1[i*4+3] = (short)f2bf(b[3]);
    }
    short8 o0, o1;
    o0[0]=s0[0]; o0[1]=s0[1]; o0[2]=s0[2]; o0[3]=s0[3]; o0[4]=s1[0]; o0[5]=s1[1]; o0[6]=s1[2]; o0[7]=s1[3];
    o1[0]=s0[4]; o1[1]=s0[5]; o1[2]=s0[6]; o1[3]=s0[7]; o1[4]=s1[4]; o1[5]=s1[5]; o1[6]=s1[6]; o1[7]=s1[7];
    const int kc = j >> 1;
    const int q2 = (j & 1) * 2;
    const int half = key >> 4, keyh = key & 15;
    unsigned short* kout = tile + kc * 1024 + half * 512 + keyh * 8;
    *(short8*)(kout + (q2    ) * 128) = o0;   // chunk (q2*16+keyh)
    *(short8*)(kout + (q2 + 1) * 128) = o1;   // chunk ((q2+1)*16+keyh)
  }
  // V: convert into LDS [key][ch], u32-packed writes
  {
    const float* vp = v + src;
#pragma unroll
    for (int i = 0; i < 4; ++i) {
      floatx4 a = *(const floatx4*)(vp + i * 4);
      unsigned lo = (unsigned)f2bf(a[0]) | ((unsigned)f2bf(a[1]) << 16);
      unsigned hi = (unsigned)f2bf(a[2]) | ((unsigned)f2bf(a[3]) << 16);
      *(unsigned*)&Vlds[key][c0 + i*4]     = lo;
      *(unsigned*)&Vlds[key][c0 + i*4 + 2] = hi;
    }
  }
  __syncthreads();
  // V fragment chunks, permuted key order: pos p <-> key (p&1)*16 + (p>>1)
  {
    const int cb = t >> 5;
    const int rem = t & 31;
    const int col = rem >> 1, qh = rem & 1;
    const int ch = cb * 16 + col;
#pragma unroll
    for (int qs = 0; qs < 2; ++qs) {
      const int quad = qh * 2 + qs;
      short8 o;
#pragma unroll
      for (int i = 0; i < 8; ++i)
        o[i] = (short)Vlds[(i & 1) * 16 + quad * 4 + (i >> 1)][ch];
      *(short8*)(tile + 4096 + cb * 512 + (quad * 16 + col) * 8) = o;
    }
  }
}

// ---------------- main fused attention ---------------------------------------
// 512 blocks x 256 threads (4 waves). Wave = 48 q-rows (3 sets of 16).
// SWAPPED QK^T: A=kf, B=qfrag (A/B fragment lane layouts are identical for
// mfma_16x16x32, so this is a pure operand exchange). Lane (col,quad) then
// holds P[key=quad*4+r (+16 for kf1)][q=s*16+col] — exactly the 8 values its
// own PV A-fragment needs under the ws V-permutation (pos p <-> key
// (p&1)*16+(p>>1)). The packed dwords f2bf(p0)|f2bf(p1)<<16 ARE the pf
// fragment. The P LDS write->read round-trip (present in every variant
// rounds 0-6; the last unvaried piece of the invariant ~1150 cyc/set chain)
// is eliminated: QK -> softmax -> PV is now a pure register pipeline.
// lsum becomes per-lane scalar (+cross-quad shuffles); l broadcast in the
// epilogue via __shfl. K/V staging/barrier structure identical to round 6.
__global__ __launch_bounds__(256, 2) void attn_main(const float* __restrict__ q,
                                                    const unsigned short* __restrict__ ws,
                                                    float* __restrict__ out) {
  __shared__ unsigned short Kv[3][TILE_USH];       // 48 KB triple-buffered

  const int bid = blockIdx.x;
  const int x8 = bid & 7;
  const int i = bid >> 3;            // 0..63
  const int w = x8 * 16 + (i & 15);  // window 0..127 (XCD-matched to prep)
  const int qb = i >> 4;             // 0..3 (192 q each)
  const int batch = w >> 4, win = w & 15;
  const int wh = win >> 2, ww = win & 3;

  const int tid = threadIdx.x;
  const int wv = tid >> 6, lane = tid & 63;
  const int col = lane & 15, quad = lane >> 4;
  const long bbase = (long)batch * (H * W * C);
  const int qbase = qb * 192 + wv * 48;
  const int loff = lane * 8;         // fragment chunk offset (ushorts), linear

  const char* wtile = (const char*)(ws + (long)w * (NKT * TILE_USH));

  auto stage = [&](int buf, int kt) {
    const char* g = wtile + ((long)kt << 14);
#pragma unroll
    for (int c = 0; c < 4; ++c) {
      const int chunk = wv * 4 + c;
      gll16(g + chunk * 1024 + lane * 16, &Kv[buf][chunk * 512]);
    }
  };

  stage(0, 0); stage(1, 1); stage(2, 2);   // fill all 3 buffers up front

  // ---- Q fragments: 3 sets x 4 kc, kept in registers ----
  short8 qfrag[3][4];
#pragma unroll
  for (int s = 0; s < 3; ++s) {
    const int qtok = qbase + s * 16 + col;
    const float* qp = q + bbase + (long)tok_off(qtok, wh, ww) * C + quad * 8;
#pragma unroll
    for (int kc = 0; kc < 4; ++kc) {
      floatx4 a = *(const floatx4*)(qp + kc * 32);
      floatx4 b = *(const floatx4*)(qp + kc * 32 + 4);
      short8 v8;
      v8[0]=(short)f2bf(a[0]); v8[1]=(short)f2bf(a[1]); v8[2]=(short)f2bf(a[2]); v8[3]=(short)f2bf(a[3]);
      v8[4]=(short)f2bf(b[0]); v8[5]=(short)f2bf(b[1]); v8[6]=(short)f2bf(b[2]); v8[7]=(short)f2bf(b[3]);
      qfrag[s][kc] = v8;
    }
  }

  // ---- analytic mask regions (wave-uniform per set) ----
  int qreg[3];
#pragma unroll
  for (int s = 0; s < 3; ++s) {
    int t0 = qbase + s * 16;
    int rr_s = t0 >> 5;
    int qh = (wh == 3) ? ((rr_s >= SH) ? 2 : 1) : 0;
    int qw = (ww == 3) ? ((t0 & 16) ? 2 : 1) : 0;
    qreg[s] = qh * 3 + qw;
  }
  const int cw0 = (ww == 3) ? 1 : 0, cw1 = (ww == 3) ? 2 : 0;
  const float MNEG = -144.2695041f;  // -100*log2(e)
  const float SC2 = 0.12751739f;     // log2(e)/sqrt(128)

  floatx4 oacc[3][8];
#pragma unroll
  for (int s = 0; s < 3; ++s)
#pragma unroll
    for (int cb = 0; cb < 8; ++cb) oacc[s][cb] = (floatx4){0.f, 0.f, 0.f, 0.f};
  float lsum[3] = {0.f, 0.f, 0.f};

  // carried pipeline state: pf (P fragments, register-built) and vf
  short8 pfc[3];
  short8 vf[8];

  // QK (swapped) + softmax -> pfc for tile kt from buffer buf
  auto qk_sm = [&](int kt, int buf) {
    short8 kf0[4], kf1[4];
#pragma unroll
    for (int kc = 0; kc < 4; ++kc) {
      kf0[kc] = *(const short8*)&Kv[buf][kc * 1024 + loff];
      kf1[kc] = *(const short8*)&Kv[buf][kc * 1024 + 512 + loff];
    }
    const int khb = (wh == 3) ? ((kt >= SH) ? 6 : 3) : 0;
    const int kr0 = khb + cw0, kr1 = khb + cw1;

    floatx4 A0[3], A1[3];
#pragma unroll
    for (int s = 0; s < 3; ++s) {
      A0[s] = (floatx4){0.f, 0.f, 0.f, 0.f};
      A1[s] = (floatx4){0.f, 0.f, 0.f, 0.f};
    }
    __builtin_amdgcn_s_setprio(1);
#pragma unroll
    for (int kc = 0; kc < 4; ++kc)
#pragma unroll
      for (int s = 0; s < 3; ++s) {
        A0[s] = __builtin_amdgcn_mfma_f32_16x16x32_bf16(kf0[kc], qfrag[s][kc], A0[s], 0, 0, 0);
        A1[s] = __builtin_amdgcn_mfma_f32_16x16x32_bf16(kf1[kc], qfrag[s][kc], A1[s], 0, 0, 0);
      }
    __builtin_amdgcn_s_setprio(0);

#pragma unroll
    for (int s = 0; s < 3; ++s) {
      const float m0 = (qreg[s] == kr0) ? 0.f : MNEG;
      const float m1 = (qreg[s] == kr1) ? 0.f : MNEG;
      float ls = 0.f;
      U8 pk;
#pragma unroll
      for (int r = 0; r < 4; ++r) {
        float p0 = __builtin_amdgcn_exp2f(fmaf(A0[s][r], SC2, m0));
        float p1 = __builtin_amdgcn_exp2f(fmaf(A1[s][r], SC2, m1));
        ls += p0 + p1;
        pk.u[r] = (unsigned)f2bf(p0) | ((unsigned)f2bf(p1) << 16);
      }
      lsum[s] += ls;
      pfc[s] = pk.s8;
    }
  };

  auto loadV = [&](int buf) {
#pragma unroll
    for (int cb = 0; cb < 8; ++cb)
      vf[cb] = *(const short8*)&Kv[buf][4096 + cb * 512 + loff];
  };
  auto pv = [&]() {
    __builtin_amdgcn_s_setprio(1);
#pragma unroll
    for (int cb = 0; cb < 8; ++cb)
#pragma unroll
      for (int s = 0; s < 3; ++s)
        oacc[s][cb] = __builtin_amdgcn_mfma_f32_16x16x32_bf16(pfc[s], vf[cb], oacc[s][cb], 0, 0, 0);
    __builtin_amdgcn_s_setprio(0);
  };

  // tile 0 staged (tiles 1,2 may still be in flight)
  asm volatile("s_waitcnt vmcnt(8)" ::: "memory");
  __builtin_amdgcn_s_barrier();

  // ---- peel tile 0: QK/SM + V load; no PV yet ----
  qk_sm(0, 0);
  loadV(0);
  asm volatile("s_waitcnt vmcnt(4) lgkmcnt(0)" ::: "memory");  // tile 1 landed; V reads done
  __builtin_amdgcn_s_barrier();

  for (int kt = 1; kt < NKT; ++kt) {
    const int buf = kt % 3;
    // stage kt+2 into buffer of kt-1 (reads drained at previous bottom)
    if (kt + 2 < NKT) stage((kt + 2) % 3, kt + 2);

    pv();                 // PV(kt-1): carried pfc/vf, independent MFMA burst
    qk_sm(kt, buf);       // register-only chain of this tile
    loadV(buf);           // V(kt) into carried regs, consumed next iteration

    if (kt + 1 < NKT) {
      if (kt + 2 < NKT) asm volatile("s_waitcnt vmcnt(4) lgkmcnt(0)" ::: "memory");
      else              asm volatile("s_waitcnt vmcnt(0) lgkmcnt(0)" ::: "memory");
      __builtin_amdgcn_s_barrier();
    }
  }
  pv();   // tail: PV(NKT-1)

  // ---- epilogue: reduce l across quads, broadcast, divide, store ----
#pragma unroll
  for (int s = 0; s < 3; ++s) {
    float l = lsum[s];
    l += __shfl_xor(l, 16);
    l += __shfl_xor(l, 32);   // l now full sum for q-token s*16+col (uniform over quads)
#pragma unroll
    for (int r = 0; r < 4; ++r) {
      float lr = __shfl(l, quad * 4 + r);   // l of q-token s*16+quad*4+r
      float inv = 1.0f / lr;
      int tok = qbase + s * 16 + quad * 4 + r;
      float* op = out + bbase + (long)tok_off(tok, wh, ww) * C + col;
#pragma unroll
      for (int cb = 0; cb < 8; ++cb) op[cb * 16] = oacc[s][cb][r] * inv;
    }
  }
}

// ---------------- fallback (self-contained, used only if ws too small) -------
#define KSTRF 136
#define VSTRF 40
#define PSTRF 40
__global__ __launch_bounds__(256, 2) void attn_fallback(
    const float* __restrict__ q, const float* __restrict__ k,
    const float* __restrict__ v, const float* __restrict__ mask,
    float* __restrict__ out) {
  __shared__ unsigned short Ks[KT * KSTRF];
  __shared__ unsigned short Vtl[C * VSTRF];
  __shared__ unsigned short Psf[4][16 * PSTRF];
  const int qtile = blockIdx.x;
  const int beta  = blockIdx.y;
  const int batch = beta >> 4;
  const int win   = beta & 15;
  const int wh = win >> 2, ww = win & 3;
  const int tid = threadIdx.x;
  const int wave = tid >> 6, lane = tid & 63;
  const int col = lane & 15, quad = lane >> 4;
  const long bbase = (long)batch * (H * W * C);
  const int qtok = qtile * 64 + wave * 16 + col;
  const float* qp = q + bbase + (long)tok_off(qtok, wh, ww) * C + quad * 8;
  short8 qfrag[4];
#pragma unroll
  for (int kc = 0; kc < 4; ++kc) {
    floatx4 a = *(const floatx4*)(qp + kc * 32);
    floatx4 b = *(const floatx4*)(qp + kc * 32 + 4);
    short8 s;
    s[0]=f2bf(a[0]); s[1]=f2bf(a[1]); s[2]=f2bf(a[2]); s[3]=f2bf(a[3]);
    s[4]=f2bf(b[0]); s[5]=f2bf(b[1]); s[6]=f2bf(b[2]); s[7]=f2bf(b[3]);
    qfrag[kc] = s;
  }
  floatx4 oacc[8];
#pragma unroll
  for (int i = 0; i < 8; ++i) oacc[i] = (floatx4){0.f,0.f,0.f,0.f};
  float mrow[4], lrow[4];
#pragma unroll
  for (int r = 0; r < 4; ++r) { mrow[r] = -1e30f; lrow[r] = 0.f; }
  const int skey = tid >> 3;
  const int sch  = (tid & 7) * 4;
  const float invscale = 0.088388347648318447f;
  const float* maskw = mask + (long)win * (NTOK * NTOK);
  const int qrow_m = qtile * 64 + wave * 16 + quad * 4;
  for (int kt = 0; kt < NKT; ++kt) {
    const int ktok0 = kt * KT;
    const long srow = bbase + (long)tok_off(ktok0 + skey, wh, ww) * C;
    const float* kp = k + srow;
    const float* vp = v + srow;
    __syncthreads();
#pragma unroll
    for (int j = 0; j < 4; ++j) {
      floatx4 f = *(const floatx4*)(kp + sch + j * 32);
      unsigned lo = (unsigned)f2bf(f[0]) | ((unsigned)f2bf(f[1]) << 16);
      unsigned hi = (unsigned)f2bf(f[2]) | ((unsigned)f2bf(f[3]) << 16);
      *(uint2*)&Ks[skey * KSTRF + sch + j * 32] = make_uint2(lo, hi);
    }
#pragma unroll
    for (int j = 0; j < 4; ++j) {
      floatx4 f = *(const floatx4*)(vp + sch + j * 32);
      int chb = sch + j * 32;
      Vtl[(chb + 0) * VSTRF + skey] = f2bf(f[0]);
      Vtl[(chb + 1) * VSTRF + skey] = f2bf(f[1]);
      Vtl[(chb + 2) * VSTRF + skey] = f2bf(f[2]);
      Vtl[(chb + 3) * VSTRF + skey] = f2bf(f[3]);
    }
    __syncthreads();
    floatx4 s0 = (floatx4){0.f,0.f,0.f,0.f};
    floatx4 s1 = (floatx4){0.f,0.f,0.f,0.f};
#pragma unroll
    for (int kc = 0; kc < 4; ++kc) {
      short8 k0 = *(const short8*)&Ks[col * KSTRF + kc * 32 + quad * 8];
      short8 k1 = *(const short8*)&Ks[(col + 16) * KSTRF + kc * 32 + quad * 8];
      s0 = __builtin_amdgcn_mfma_f32_16x16x32_bf16(qfrag[kc], k0, s0, 0, 0, 0);
      s1 = __builtin_amdgcn_mfma_f32_16x16x32_bf16(qfrag[kc], k1, s1, 0, 0, 0);
    }
    float mk0[4], mk1[4];
    const float* mp = maskw + (long)qrow_m * NTOK + ktok0 + col;
#pragma unroll
    for (int r = 0; r < 4; ++r) { mk0[r] = mp[r * NTOK]; mk1[r] = mp[r * NTOK + 16]; }
#pragma unroll
    for (int r = 0; r < 4; ++r) {
      float a0 = s0[r] * invscale + mk0[r];
      float a1 = s1[r] * invscale + mk1[r];
      float mx = fmaxf(a0, a1);
      mx = fmaxf(mx, __shfl_xor(mx, 1)); mx = fmaxf(mx, __shfl_xor(mx, 2));
      mx = fmaxf(mx, __shfl_xor(mx, 4)); mx = fmaxf(mx, __shfl_xor(mx, 8));
      float mnew = fmaxf(mrow[r], mx);
      float alpha = __expf(mrow[r] - mnew);
      float p0 = __expf(a0 - mnew);
      float p1 = __expf(a1 - mnew);
      float rs = p0 + p1;
      rs += __shfl_xor(rs, 1); rs += __shfl_xor(rs, 2);
      rs += __shfl_xor(rs, 4); rs += __shfl_xor(rs, 8);
      lrow[r] = lrow[r] * alpha + rs;
      mrow[r] = mnew;
#pragma unroll
      for (int cb = 0; cb < 8; ++cb) oacc[cb][r] *= alpha;
      Psf[wave][(quad * 4 + r) * PSTRF + col]      = f2bf(p0);
      Psf[wave][(quad * 4 + r) * PSTRF + 16 + col] = f2bf(p1);
    }
    __syncthreads();
    short8 pf = *(const short8*)&Psf[wave][col * PSTRF + quad * 8];
#pragma unroll
    for (int cb = 0; cb < 8; ++cb) {
      short8 vf = *(const short8*)&Vtl[(cb * 16 + col) * VSTRF + quad * 8];
      oacc[cb] = __builtin_amdgcn_mfma_f32_16x16x32_bf16(pf, vf, oacc[cb], 0, 0, 0);
    }
  }
#pragma unroll
  for (int r = 0; r < 4; ++r) {
    float inv_l = 1.0f / lrow[r];
    int tok = qtile * 64 + wave * 16 + quad * 4 + r;
    float* op = out + bbase + (long)tok_off(tok, wh, ww) * C + col;
#pragma unroll
    for (int cb = 0; cb < 8; ++cb) op[cb * 16] = oacc[cb][r] * inv_l;
  }
}

extern "C" void kernel_launch(void* const* d_in, const int* in_sizes, int n_in,
                              void* d_out, int out_size, void* d_ws, size_t ws_size,
                              hipStream_t stream) {
  const float* q    = (const float*)d_in[0];
  const float* k    = (const float*)d_in[1];
  const float* v    = (const float*)d_in[2];
  const float* mask = (const float*)d_in[3];
  float* out = (float*)d_out;
  if (ws_size >= (size_t)WS_NEED) {
    prep_kernel<<<128 * NKT, 256, 0, stream>>>(k, v, (unsigned short*)d_ws);
    attn_main<<<512, 256, 0, stream>>>(q, (const unsigned short*)d_ws, out);
  } else {
    attn_fallback<<<dim3(12, 128), dim3(256), 0, stream>>>(q, k, v, mask, out);
  }
}

// Round 8
// 241.621 us; speedup vs baseline: 1.0524x; 1.0209x over previous
//
#include <hip/hip_runtime.h>

// Problem constants: B=8, H=96, W=128, C=128, NS=4, with_shift=1
#define H 96
#define W 128
#define C 128
#define WSH 24
#define WSW 32
#define NTOK 768
#define SH 12
#define SW 16
#define KT 32        // keys per tile
#define NKT 24       // tiles per window (each tile = one spatial row)
// ws tile: K-frags 8KB + V-frags 8KB, chunk index == lane (conflict-free b128)
#define TILE_USH 8192                  // 16384 B
#define WS_NEED (128L * NKT * TILE_USH * 2)  // 50,331,648 bytes

typedef __attribute__((ext_vector_type(8))) short short8;
typedef __attribute__((ext_vector_type(4))) float floatx4;

union U8 { short8 s8; unsigned u[4]; };

__device__ inline unsigned short f2bf(float f) {
  union { float f; unsigned u; } un; un.f = f;
  unsigned r = un.u + 0x7FFF + ((un.u >> 16) & 1);
  return (unsigned short)(r >> 16);
}

// window token -> global spatial offset (y*W + x), folding the shift-roll
__device__ inline int tok_off(int tok, int wh, int ww) {
  int r = tok >> 5;
  int cc = tok & 31;
  int y = wh * WSH + r + SH; if (y >= H) y -= H;
  int x = ww * WSW + cc + SW; if (x >= W) x -= W;
  return y * W + x;
}

// async global->LDS, 16B per lane, LDS dst = wave-uniform base + lane*16
__device__ inline void gll16(const void* g, void* lds) {
  __builtin_amdgcn_global_load_lds(
      (const __attribute__((address_space(1))) unsigned int*)g,
      (__attribute__((address_space(3))) unsigned int*)lds, 16, 0, 0);
}

// ---------------- prep: fp32 K,V -> bf16 MFMA-fragment tiles in ws ----------
// (unchanged from round 7 — passing)
__global__ __launch_bounds__(256) void prep_kernel(const float* __restrict__ k,
                                                   const float* __restrict__ v,
                                                   unsigned short* __restrict__ ws) {
  __shared__ unsigned short Vlds[KT][136];
  const int bid = blockIdx.x;               // 3072 blocks
  const int xcd = bid & 7;
  const int jj = bid >> 3;                  // 0..383
  const int w = xcd * 16 + (jj & 15);       // window 0..127, on XCD w>>4
  const int kt = jj >> 4;                   // 0..23
  const int batch = w >> 4, win = w & 15;
  const int wh = win >> 2, ww = win & 3;
  int y = wh * WSH + kt + SH; if (y >= H) y -= H;

  const int t = threadIdx.x;
  const int key = t >> 3;           // 0..31
  const int j = t & 7;              // channel group of 16
  const int c0 = j * 16;
  int x = ww * WSW + key + SW; if (x >= W) x -= W;
  const long src = ((long)batch * H * W + (long)y * W + x) * C + c0;
  unsigned short* tile = ws + ((long)w * NKT + kt) * TILE_USH;

  // K: convert 16 channels -> two fragment chunks
  {
    const float* kp = k + src;
    short8 s0, s1;
#pragma unroll
    for (int i = 0; i < 2; ++i) {
      floatx4 a = *(const floatx4*)(kp + i * 8);
      floatx4 b = *(const floatx4*)(kp + i * 8 + 4);
      s0[i*4+0] = (short)f2bf(a[0]); s0[i*4+1] = (short)f2bf(a[1]);
      s0[i*4+2] = (short)f2bf(a[2]); s0[i*4+3] = (short)f2bf(a[3]);
      s1[i*4+0] = (short)f2bf(b[0]); s1[i*4+1] = (short)f2bf(b[1]);
      s1[i*4+2] = (short)f2bf(b[2]); s1[i*4+3] = (short)f2bf(b[3]);
    }
    short8 o0, o1;
    o0[0]=s0[0]; o0[1]=s0[1]; o0[2]=s0[2]; o0[3]=s0[3]; o0[4]=s1[0]; o0[5]=s1[1]; o0[6]=s1[2]; o0[7]=s1[3];
    o1[0]=s0[4]; o1[1]=s0[5]; o1[2]=s0[6]; o1[3]=s0[7]; o1[4]=s1[4]; o1[5]=s1[5]; o1[6]=s1[6]; o1[7]=s1[7];
    const int kc = j >> 1;
    const int q2 = (j & 1) * 2;
    const int half = key >> 4, keyh = key & 15;
    unsigned short* kout = tile + kc * 1024 + half * 512 + keyh * 8;
    *(short8*)(kout + (q2    ) * 128) = o0;   // chunk (q2*16+keyh)
    *(short8*)(kout + (q2 + 1) * 128) = o1;   // chunk ((q2+1)*16+keyh)
  }
  // V: convert into LDS [key][ch], u32-packed writes
  {
    const float* vp = v + src;
#pragma unroll
    for (int i = 0; i < 4; ++i) {
      floatx4 a = *(const floatx4*)(vp + i * 4);
      unsigned lo = (unsigned)f2bf(a[0]) | ((unsigned)f2bf(a[1]) << 16);
      unsigned hi = (unsigned)f2bf(a[2]) | ((unsigned)f2bf(a[3]) << 16);
      *(unsigned*)&Vlds[key][c0 + i*4]     = lo;
      *(unsigned*)&Vlds[key][c0 + i*4 + 2] = hi;
    }
  }
  __syncthreads();
  // V fragment chunks, permuted key order: pos p <-> key (p&1)*16 + (p>>1)
  {
    const int cb = t >> 5;
    const int rem = t & 31;
    const int col = rem >> 1, qh = rem & 1;
    const int ch = cb * 16 + col;
#pragma unroll
    for (int qs = 0; qs < 2; ++qs) {
      const int quad = qh * 2 + qs;
      short8 o;
#pragma unroll
      for (int i = 0; i < 8; ++i)
        o[i] = (short)Vlds[(i & 1) * 16 + quad * 4 + (i >> 1)][ch];
      *(short8*)(tile + 4096 + cb * 512 + (quad * 16 + col) * 8) = o;
    }
  }
}

// ---------------- main fused attention ---------------------------------------
// 768 blocks x 256 threads (4 waves), 3 blocks/CU = 3 waves/SIMD. Wave = 32
// q-rows (2 sets of 16); 6 q-blocks per window. Round 7 left a clean machine
// (0 bank conflicts, register-only P path, counted vmcnt, L2-resident ws)
// still at ~27% issue occupancy with 2 waves/SIMD — pure per-wave dependency
// stall. The third independent block per CU (own barrier domain, uncorrelated
// phase) fills the issue gap; per-wave VGPR drops to ~100 (<=170 needed for
// 3 waves/SIMD), LDS 48KB x 3 = 144 <= 160 KB.
// SWAPPED QK^T (A=kf, B=qfrag): lane (col,quad) holds P[key=quad*4+r(+16)]
// [q=s*16+col] == its own PV A-fragment under the ws V-permutation; packed
// dwords f2bf(p0)|f2bf(p1)<<16 ARE the pf fragment (round 7, verified).
__global__ __launch_bounds__(256, 3) void attn_main(const float* __restrict__ q,
                                                    const unsigned short* __restrict__ ws,
                                                    float* __restrict__ out) {
  __shared__ unsigned short Kv[3][TILE_USH];       // 48 KB triple-buffered

  const int bid = blockIdx.x;        // 0..767
  const int x8 = bid & 7;
  const int i = bid >> 3;            // 0..95
  const int w = x8 * 16 + (i & 15);  // window 0..127 (XCD-matched to prep)
  const int qb = i >> 4;             // 0..5 (128 q each)
  const int batch = w >> 4, win = w & 15;
  const int wh = win >> 2, ww = win & 3;

  const int tid = threadIdx.x;
  const int wv = tid >> 6, lane = tid & 63;
  const int col = lane & 15, quad = lane >> 4;
  const long bbase = (long)batch * (H * W * C);
  const int qbase = qb * 128 + wv * 32;   // multiple of 32
  const int loff = lane * 8;         // fragment chunk offset (ushorts), linear

  const char* wtile = (const char*)(ws + (long)w * (NKT * TILE_USH));

  auto stage = [&](int buf, int kt) {
    const char* g = wtile + ((long)kt << 14);
#pragma unroll
    for (int c = 0; c < 4; ++c) {
      const int chunk = wv * 4 + c;
      gll16(g + chunk * 1024 + lane * 16, &Kv[buf][chunk * 512]);
    }
  };

  stage(0, 0); stage(1, 1); stage(2, 2);   // fill all 3 buffers up front

  // ---- Q fragments: 2 sets x 4 kc, kept in registers ----
  short8 qfrag[2][4];
#pragma unroll
  for (int s = 0; s < 2; ++s) {
    const int qtok = qbase + s * 16 + col;
    const float* qp = q + bbase + (long)tok_off(qtok, wh, ww) * C + quad * 8;
#pragma unroll
    for (int kc = 0; kc < 4; ++kc) {
      floatx4 a = *(const floatx4*)(qp + kc * 32);
      floatx4 b = *(const floatx4*)(qp + kc * 32 + 4);
      short8 v8;
      v8[0]=(short)f2bf(a[0]); v8[1]=(short)f2bf(a[1]); v8[2]=(short)f2bf(a[2]); v8[3]=(short)f2bf(a[3]);
      v8[4]=(short)f2bf(b[0]); v8[5]=(short)f2bf(b[1]); v8[6]=(short)f2bf(b[2]); v8[7]=(short)f2bf(b[3]);
      qfrag[s][kc] = v8;
    }
  }

  // ---- analytic mask regions (wave-uniform per set) ----
  int qreg[2];
#pragma unroll
  for (int s = 0; s < 2; ++s) {
    int t0 = qbase + s * 16;
    int rr_s = t0 >> 5;
    int qh = (wh == 3) ? ((rr_s >= SH) ? 2 : 1) : 0;
    int qw = (ww == 3) ? ((t0 & 16) ? 2 : 1) : 0;
    qreg[s] = qh * 3 + qw;
  }
  const int cw0 = (ww == 3) ? 1 : 0, cw1 = (ww == 3) ? 2 : 0;
  const float MNEG = -144.2695041f;  // -100*log2(e)
  const float SC2 = 0.12751739f;     // log2(e)/sqrt(128)

  floatx4 oacc[2][8];
#pragma unroll
  for (int s = 0; s < 2; ++s)
#pragma unroll
    for (int cb = 0; cb < 8; ++cb) oacc[s][cb] = (floatx4){0.f, 0.f, 0.f, 0.f};
  float lsum[2] = {0.f, 0.f};

  // carried pipeline state: pf (P fragments, register-built) and vf
  short8 pfc[2];
  short8 vf[8];

  // QK (swapped) + softmax -> pfc for tile kt from buffer buf
  auto qk_sm = [&](int kt, int buf) {
    short8 kf0[4], kf1[4];
#pragma unroll
    for (int kc = 0; kc < 4; ++kc) {
      kf0[kc] = *(const short8*)&Kv[buf][kc * 1024 + loff];
      kf1[kc] = *(const short8*)&Kv[buf][kc * 1024 + 512 + loff];
    }
    const int khb = (wh == 3) ? ((kt >= SH) ? 6 : 3) : 0;
    const int kr0 = khb + cw0, kr1 = khb + cw1;

    floatx4 A0[2], A1[2];
#pragma unroll
    for (int s = 0; s < 2; ++s) {
      A0[s] = (floatx4){0.f, 0.f, 0.f, 0.f};
      A1[s] = (floatx4){0.f, 0.f, 0.f, 0.f};
    }
    __builtin_amdgcn_s_setprio(1);
#pragma unroll
    for (int kc = 0; kc < 4; ++kc)
#pragma unroll
      for (int s = 0; s < 2; ++s) {
        A0[s] = __builtin_amdgcn_mfma_f32_16x16x32_bf16(kf0[kc], qfrag[s][kc], A0[s], 0, 0, 0);
        A1[s] = __builtin_amdgcn_mfma_f32_16x16x32_bf16(kf1[kc], qfrag[s][kc], A1[s], 0, 0, 0);
      }
    __builtin_amdgcn_s_setprio(0);

#pragma unroll
    for (int s = 0; s < 2; ++s) {
      const float m0 = (qreg[s] == kr0) ? 0.f : MNEG;
      const float m1 = (qreg[s] == kr1) ? 0.f : MNEG;
      float ls = 0.f;
      U8 pk;
#pragma unroll
      for (int r = 0; r < 4; ++r) {
        float p0 = __builtin_amdgcn_exp2f(fmaf(A0[s][r], SC2, m0));
        float p1 = __builtin_amdgcn_exp2f(fmaf(A1[s][r], SC2, m1));
        ls += p0 + p1;
        pk.u[r] = (unsigned)f2bf(p0) | ((unsigned)f2bf(p1) << 16);
      }
      lsum[s] += ls;
      pfc[s] = pk.s8;
    }
  };

  auto loadV = [&](int buf) {
#pragma unroll
    for (int cb = 0; cb < 8; ++cb)
      vf[cb] = *(const short8*)&Kv[buf][4096 + cb * 512 + loff];
  };
  auto pv = [&]() {
    __builtin_amdgcn_s_setprio(1);
#pragma unroll
    for (int cb = 0; cb < 8; ++cb)
#pragma unroll
      for (int s = 0; s < 2; ++s)
        oacc[s][cb] = __builtin_amdgcn_mfma_f32_16x16x32_bf16(pfc[s], vf[cb], oacc[s][cb], 0, 0, 0);
    __builtin_amdgcn_s_setprio(0);
  };

  // tile 0 staged (tiles 1,2 may still be in flight)
  asm volatile("s_waitcnt vmcnt(8)" ::: "memory");
  __builtin_amdgcn_s_barrier();

  // ---- peel tile 0: QK/SM + V load; no PV yet ----
  qk_sm(0, 0);
  loadV(0);
  asm volatile("s_waitcnt vmcnt(4) lgkmcnt(0)" ::: "memory");  // tile 1 landed; V reads done
  __builtin_amdgcn_s_barrier();

  for (int kt = 1; kt < NKT; ++kt) {
    const int buf = kt % 3;
    // stage kt+2 into buffer of kt-1 (reads drained at previous bottom)
    if (kt + 2 < NKT) stage((kt + 2) % 3, kt + 2);

    pv();                 // PV(kt-1): carried pfc/vf, independent MFMA burst
    qk_sm(kt, buf);       // register-only chain of this tile
    loadV(buf);           // V(kt) into carried regs, consumed next iteration

    if (kt + 1 < NKT) {
      if (kt + 2 < NKT) asm volatile("s_waitcnt vmcnt(4) lgkmcnt(0)" ::: "memory");
      else              asm volatile("s_waitcnt vmcnt(0) lgkmcnt(0)" ::: "memory");
      __builtin_amdgcn_s_barrier();
    }
  }
  pv();   // tail: PV(NKT-1)

  // ---- epilogue: reduce l across quads, broadcast, divide, store ----
#pragma unroll
  for (int s = 0; s < 2; ++s) {
    float l = lsum[s];
    l += __shfl_xor(l, 16);
    l += __shfl_xor(l, 32);   // l now full sum for q-token s*16+col (uniform over quads)
#pragma unroll
    for (int r = 0; r < 4; ++r) {
      float lr = __shfl(l, quad * 4 + r);   // l of q-token s*16+quad*4+r
      float inv = 1.0f / lr;
      int tok = qbase + s * 16 + quad * 4 + r;
      float* op = out + bbase + (long)tok_off(tok, wh, ww) * C + col;
#pragma unroll
      for (int cb = 0; cb < 8; ++cb) op[cb * 16] = oacc[s][cb][r] * inv;
    }
  }
}

// ---------------- fallback (self-contained, used only if ws too small) -------
#define KSTRF 136
#define VSTRF 40
#define PSTRF 40
__global__ __launch_bounds__(256, 2) void attn_fallback(
    const float* __restrict__ q, const float* __restrict__ k,
    const float* __restrict__ v, const float* __restrict__ mask,
    float* __restrict__ out) {
  __shared__ unsigned short Ks[KT * KSTRF];
  __shared__ unsigned short Vtl[C * VSTRF];
  __shared__ unsigned short Psf[4][16 * PSTRF];
  const int qtile = blockIdx.x;
  const int beta  = blockIdx.y;
  const int batch = beta >> 4;
  const int win   = beta & 15;
  const int wh = win >> 2, ww = win & 3;
  const int tid = threadIdx.x;
  const int wave = tid >> 6, lane = tid & 63;
  const int col = lane & 15, quad = lane >> 4;
  const long bbase = (long)batch * (H * W * C);
  const int qtok = qtile * 64 + wave * 16 + col;
  const float* qp = q + bbase + (long)tok_off(qtok, wh, ww) * C + quad * 8;
  short8 qfrag[4];
#pragma unroll
  for (int kc = 0; kc < 4; ++kc) {
    floatx4 a = *(const floatx4*)(qp + kc * 32);
    floatx4 b = *(const floatx4*)(qp + kc * 32 + 4);
    short8 s;
    s[0]=f2bf(a[0]); s[1]=f2bf(a[1]); s[2]=f2bf(a[2]); s[3]=f2bf(a[3]);
    s[4]=f2bf(b[0]); s[5]=f2bf(b[1]); s[6]=f2bf(b[2]); s[7]=f2bf(b[3]);
    qfrag[kc] = s;
  }
  floatx4 oacc[8];
#pragma unroll
  for (int i = 0; i < 8; ++i) oacc[i] = (floatx4){0.f,0.f,0.f,0.f};
  float mrow[4], lrow[4];
#pragma unroll
  for (int r = 0; r < 4; ++r) { mrow[r] = -1e30f; lrow[r] = 0.f; }
  const int skey = tid >> 3;
  const int sch  = (tid & 7) * 4;
  const float invscale = 0.088388347648318447f;
  const float* maskw = mask + (long)win * (NTOK * NTOK);
  const int qrow_m = qtile * 64 + wave * 16 + quad * 4;
  for (int kt = 0; kt < NKT; ++kt) {
    const int ktok0 = kt * KT;
    const long srow = bbase + (long)tok_off(ktok0 + skey, wh, ww) * C;
    const float* kp = k + srow;
    const float* vp = v + srow;
    __syncthreads();
#pragma unroll
    for (int j = 0; j < 4; ++j) {
      floatx4 f = *(const floatx4*)(kp + sch + j * 32);
      unsigned lo = (unsigned)f2bf(f[0]) | ((unsigned)f2bf(f[1]) << 16);
      unsigned hi = (unsigned)f2bf(f[2]) | ((unsigned)f2bf(f[3]) << 16);
      *(uint2*)&Ks[skey * KSTRF + sch + j * 32] = make_uint2(lo, hi);
    }
#pragma unroll
    for (int j = 0; j < 4; ++j) {
      floatx4 f = *(const floatx4*)(vp + sch + j * 32);
      int chb = sch + j * 32;
      Vtl[(chb + 0) * VSTRF + skey] = f2bf(f[0]);
      Vtl[(chb + 1) * VSTRF + skey] = f2bf(f[1]);
      Vtl[(chb + 2) * VSTRF + skey] = f2bf(f[2]);
      Vtl[(chb + 3) * VSTRF + skey] = f2bf(f[3]);
    }
    __syncthreads();
    floatx4 s0 = (floatx4){0.f,0.f,0.f,0.f};
    floatx4 s1 = (floatx4){0.f,0.f,0.f,0.f};
#pragma unroll
    for (int kc = 0; kc < 4; ++kc) {
      short8 k0 = *(const short8*)&Ks[col * KSTRF + kc * 32 + quad * 8];
      short8 k1 = *(const short8*)&Ks[(col + 16) * KSTRF + kc * 32 + quad * 8];
      s0 = __builtin_amdgcn_mfma_f32_16x16x32_bf16(qfrag[kc], k0, s0, 0, 0, 0);
      s1 = __builtin_amdgcn_mfma_f32_16x16x32_bf16(qfrag[kc], k1, s1, 0, 0, 0);
    }
    float mk0[4], mk1[4];
    const float* mp = maskw + (long)qrow_m * NTOK + ktok0 + col;
#pragma unroll
    for (int r = 0; r < 4; ++r) { mk0[r] = mp[r * NTOK]; mk1[r] = mp[r * NTOK + 16]; }
#pragma unroll
    for (int r = 0; r < 4; ++r) {
      float a0 = s0[r] * invscale + mk0[r];
      float a1 = s1[r] * invscale + mk1[r];
      float mx = fmaxf(a0, a1);
      mx = fmaxf(mx, __shfl_xor(mx, 1)); mx = fmaxf(mx, __shfl_xor(mx, 2));
      mx = fmaxf(mx, __shfl_xor(mx, 4)); mx = fmaxf(mx, __shfl_xor(mx, 8));
      float mnew = fmaxf(mrow[r], mx);
      float alpha = __expf(mrow[r] - mnew);
      float p0 = __expf(a0 - mnew);
      float p1 = __expf(a1 - mnew);
      float rs = p0 + p1;
      rs += __shfl_xor(rs, 1); rs += __shfl_xor(rs, 2);
      rs += __shfl_xor(rs, 4); rs += __shfl_xor(rs, 8);
      lrow[r] = lrow[r] * alpha + rs;
      mrow[r] = mnew;
#pragma unroll
      for (int cb = 0; cb < 8; ++cb) oacc[cb][r] *= alpha;
      Psf[wave][(quad * 4 + r) * PSTRF + col]      = f2bf(p0);
      Psf[wave][(quad * 4 + r) * PSTRF + 16 + col] = f2bf(p1);
    }
    __syncthreads();
    short8 pf = *(const short8*)&Psf[wave][col * PSTRF + quad * 8];
#pragma unroll
    for (int cb = 0; cb < 8; ++cb) {
      short8 vf = *(const short8*)&Vtl[(cb * 16 + col) * VSTRF + quad * 8];
      oacc[cb] = __builtin_amdgcn_mfma_f32_16x16x32_bf16(pf, vf, oacc[cb], 0, 0, 0);
    }
  }
#pragma unroll
  for (int r = 0; r < 4; ++r) {
    float inv_l = 1.0f / lrow[r];
    int tok = qtile * 64 + wave * 16 + quad * 4 + r;
    float* op = out + bbase + (long)tok_off(tok, wh, ww) * C + col;
#pragma unroll
    for (int cb = 0; cb < 8; ++cb) op[cb * 16] = oacc[cb][r] * inv_l;
  }
}

extern "C" void kernel_launch(void* const* d_in, const int* in_sizes, int n_in,
                              void* d_out, int out_size, void* d_ws, size_t ws_size,
                              hipStream_t stream) {
  const float* q    = (const float*)d_in[0];
  const float* k    = (const float*)d_in[1];
  const float* v    = (const float*)d_in[2];
  const float* mask = (const float*)d_in[3];
  float* out = (float*)d_out;
  if (ws_size >= (size_t)WS_NEED) {
    prep_kernel<<<128 * NKT, 256, 0, stream>>>(k, v, (unsigned short*)d_ws);
    attn_main<<<768, 256, 0, stream>>>(q, (const unsigned short*)d_ws, out);
  } else {
    attn_fallback<<<dim3(12, 128), dim3(256), 0, stream>>>(q, k, v, mask, out);
  }
}